// Round 1
// baseline (1956.136 us; speedup 1.0000x reference)
//
#include <hip/hip_runtime.h>
#include <hip/hip_bf16.h>

#define BATCH 4
#define SEQ   4096
#define DMODEL 1024
#define NH    16
#define DH    64
#define NCHUNK 32
#define CHUNKSZ 128
#define FEPS  1e-6f

typedef unsigned short ushort_t;

__device__ __forceinline__ float bf2f(ushort_t u) {
    union { unsigned int i; float f; } x; x.i = ((unsigned int)u) << 16; return x.f;
}
__device__ __forceinline__ ushort_t f2bf(float f) {
    union { float f; unsigned int i; } x; x.f = f;
    unsigned int lsb = (x.i >> 16) & 1u;
    x.i += 0x7fffu + lsb;   // round-to-nearest-even
    return (ushort_t)(x.i >> 16);
}

// ---------------------------------------------------------------------------
// GEMM: C = op(A @ W). A [M,K] row-major, W [K,N] row-major.
// MODE 0: A=f32, epilogue feature(elu+1), out bf16 scattered to [b,h,t,d]
// MODE 1: A=f32, plain, out bf16 scattered to [b,h,t,d]
// MODE 2: A=bf16, +bias, out f32 row-major
// ---------------------------------------------------------------------------
#define BM 128
#define BN 128
#define BKK 16

template<int MODE>
__global__ __launch_bounds__(256) void gemm_k(const void* __restrict__ Ap,
                                              const float* __restrict__ W,
                                              const float* __restrict__ bias,
                                              void* __restrict__ Cp,
                                              int M, int N, int K)
{
    __shared__ float As[BKK][BM + 4];
    __shared__ float Bs[BKK][BN + 4];
    const int tid = threadIdx.x;
    const int m0 = blockIdx.x * BM;
    const int n0 = blockIdx.y * BN;
    float acc[8][8];
#pragma unroll
    for (int i = 0; i < 8; i++)
#pragma unroll
        for (int j = 0; j < 8; j++) acc[i][j] = 0.f;
    const int tm = (tid >> 4) << 3;
    const int tn = (tid & 15) << 3;

    for (int k0 = 0; k0 < K; k0 += BKK) {
#pragma unroll
        for (int i = 0; i < 8; i++) {
            int idx = tid + i * 256;          // 0..2047 over 128x16 A tile
            int m = idx >> 4, kk = idx & 15;
            float v;
            if (MODE == 2) v = bf2f(((const ushort_t*)Ap)[(size_t)(m0 + m) * K + k0 + kk]);
            else           v = ((const float*)Ap)[(size_t)(m0 + m) * K + k0 + kk];
            As[kk][m] = v;
        }
#pragma unroll
        for (int i = 0; i < 8; i++) {
            int idx = tid + i * 256;          // 0..2047 over 16x128 B tile
            int kk = idx >> 7, n = idx & 127;
            Bs[kk][n] = W[(size_t)(k0 + kk) * N + n0 + n];
        }
        __syncthreads();
#pragma unroll
        for (int kk = 0; kk < BKK; kk++) {
            float a[8], b[8];
#pragma unroll
            for (int i = 0; i < 8; i++) a[i] = As[kk][tm + i];
#pragma unroll
            for (int j = 0; j < 8; j++) b[j] = Bs[kk][tn + j];
#pragma unroll
            for (int i = 0; i < 8; i++)
#pragma unroll
                for (int j = 0; j < 8; j++) acc[i][j] = fmaf(a[i], b[j], acc[i][j]);
        }
        __syncthreads();
    }

#pragma unroll
    for (int i = 0; i < 8; i++) {
        int m = m0 + tm + i;
#pragma unroll
        for (int j = 0; j < 8; j++) {
            int n = n0 + tn + j;
            float v = acc[i][j];
            if (MODE == 0) v = (v > 0.f) ? (v + 1.f) : __expf(v);
            if (MODE == 2) {
                ((float*)Cp)[(size_t)m * N + n] = v + bias[n];
            } else {
                int b_ = m >> 12, t_ = m & 4095, h_ = n >> 6, d_ = n & 63;
                ((ushort_t*)Cp)[((((size_t)b_ * NH + h_) * SEQ + t_) << 6) + d_] = f2bf(v);
            }
        }
    }
}

// ---------------------------------------------------------------------------
// Z[b,h,t] = 1/(sum_d Q[b,h,t,d] * cumsum_{h'<=h} K[b,h',t,d] + eps)
// one 64-lane block per (b,t)
// ---------------------------------------------------------------------------
__global__ __launch_bounds__(64) void z_k(const ushort_t* __restrict__ Q,
                                          const ushort_t* __restrict__ K,
                                          float* __restrict__ Z)
{
    int bt = blockIdx.x;
    int b_ = bt >> 12, t_ = bt & 4095;
    int d = threadIdx.x;
    float ck = 0.f;
    for (int h = 0; h < NH; h++) {
        size_t idx = ((((size_t)b_ * NH + h) * SEQ + t_) << 6) + d;
        ck += bf2f(K[idx]);
        float p = bf2f(Q[idx]) * ck;
#pragma unroll
        for (int off = 32; off; off >>= 1) p += __shfl_down(p, off, 64);
        if (d == 0) Z[((size_t)b_ * NH + h) * SEQ + t_] = 1.f / (p + FEPS);
    }
}

// ---------------------------------------------------------------------------
// Per-chunk S_local[b,h,c] = K_c^T V_c   (64x64, sum over 128 rows)
// ---------------------------------------------------------------------------
__global__ __launch_bounds__(256) void kv_k(const ushort_t* __restrict__ Kf,
                                            const ushort_t* __restrict__ Vf,
                                            float* __restrict__ Sloc)
{
    int blk = blockIdx.x;
    int c  = blk & (NCHUNK - 1);
    int bh = blk >> 5;
    size_t rowbase = ((size_t)bh * SEQ + (size_t)c * CHUNKSZ) * DH;
    const ushort4* K4 = (const ushort4*)(Kf + rowbase);
    const ushort4* V4 = (const ushort4*)(Vf + rowbase);
    __shared__ float Ks[CHUNKSZ][DH];
    __shared__ float Vs[CHUNKSZ][DH];
    int tid = threadIdx.x;
#pragma unroll
    for (int i = 0; i < 8; i++) {
        int idx = tid + i * 256;              // 2048 ushort4 = 128x64
        ushort4 uk = K4[idx], uv = V4[idx];
        ((float4*)Ks)[idx] = make_float4(bf2f(uk.x), bf2f(uk.y), bf2f(uk.z), bf2f(uk.w));
        ((float4*)Vs)[idx] = make_float4(bf2f(uv.x), bf2f(uv.y), bf2f(uv.z), bf2f(uv.w));
    }
    __syncthreads();
    int d  = tid >> 2;
    int e0 = (tid & 3) << 4;
    float acc[16];
#pragma unroll
    for (int e = 0; e < 16; e++) acc[e] = 0.f;
    for (int j = 0; j < CHUNKSZ; j++) {
        float kv = Ks[j][d];
#pragma unroll
        for (int e = 0; e < 16; e++) acc[e] = fmaf(kv, Vs[j][e0 + e], acc[e]);
    }
    float* out = Sloc + (size_t)blk * DH * DH + d * DH + e0;
#pragma unroll
    for (int e = 0; e < 16; e++) out[e] = acc[e];
}

// ---------------------------------------------------------------------------
// In-place exclusive prefix over chunks: Sloc[bh][c] <- sum_{c'<c} Sloc[bh][c']
// ---------------------------------------------------------------------------
__global__ __launch_bounds__(256) void scan_k(float* __restrict__ Sloc)
{
    int bh = blockIdx.x;
    int tid = threadIdx.x;
    float* base = Sloc + (size_t)bh * NCHUNK * DH * DH;
    float acc[16];
#pragma unroll
    for (int i = 0; i < 16; i++) acc[i] = 0.f;
    for (int cc = 0; cc < NCHUNK; cc++) {
        float* p = base + (size_t)cc * DH * DH;
#pragma unroll
        for (int i = 0; i < 16; i++) {
            int idx = tid + i * 256;
            float tmp = p[idx];
            p[idx] = acc[i];
            acc[i] += tmp;
        }
    }
}

// ---------------------------------------------------------------------------
// Per-chunk output: out = (tril(Q K^T)) V + Q S_pre, scaled by Z,
// written bf16 to A in [ (b*T+t) , h*64+d ] row-major layout.
// 128 threads = one per chunk row.
// ---------------------------------------------------------------------------
__global__ __launch_bounds__(128) void attn_k(const ushort_t* __restrict__ Qf,
                                              const ushort_t* __restrict__ Kf,
                                              const ushort_t* __restrict__ Vf,
                                              const float* __restrict__ Sloc,
                                              const float* __restrict__ Z,
                                              ushort_t* __restrict__ A)
{
    int blk = blockIdx.x;
    int c  = blk & (NCHUNK - 1);
    int bh = blk >> 5;
    int b_ = bh >> 4, h_ = bh & 15;
    size_t rowbase = ((size_t)bh * SEQ + (size_t)c * CHUNKSZ) * DH;
    const ushort4* K4 = (const ushort4*)(Kf + rowbase);
    const ushort4* V4 = (const ushort4*)(Vf + rowbase);
    const float4*  S4 = (const float4*)(Sloc + (size_t)blk * DH * DH);
    __shared__ float Ks[CHUNKSZ][DH];
    __shared__ float Vs[CHUNKSZ][DH];
    __shared__ float Ss[DH][DH];
    int tid = threadIdx.x;
#pragma unroll
    for (int i = 0; i < 16; i++) {
        int idx = tid + i * 128;              // 2048 ushort4
        ushort4 uk = K4[idx], uv = V4[idx];
        ((float4*)Ks)[idx] = make_float4(bf2f(uk.x), bf2f(uk.y), bf2f(uk.z), bf2f(uk.w));
        ((float4*)Vs)[idx] = make_float4(bf2f(uv.x), bf2f(uv.y), bf2f(uv.z), bf2f(uv.w));
    }
#pragma unroll
    for (int i = 0; i < 8; i++) {
        int idx = tid + i * 128;              // 1024 float4 = 64x64
        ((float4*)Ss)[idx] = S4[idx];
    }
    float q[DH];
    {
        const ushort4* Q4 = (const ushort4*)(Qf + rowbase + (size_t)tid * DH);
#pragma unroll
        for (int d4 = 0; d4 < 16; d4++) {
            ushort4 u = Q4[d4];
            q[d4 * 4 + 0] = bf2f(u.x); q[d4 * 4 + 1] = bf2f(u.y);
            q[d4 * 4 + 2] = bf2f(u.z); q[d4 * 4 + 3] = bf2f(u.w);
        }
    }
    __syncthreads();

    float out[DH];
#pragma unroll
    for (int e = 0; e < DH; e++) out[e] = 0.f;

    for (int j = 0; j < CHUNKSZ; j++) {
        float a = 0.f;
#pragma unroll
        for (int d = 0; d < DH; d++) a = fmaf(q[d], Ks[j][d], a);
        a = (j <= tid) ? a : 0.f;             // causal mask (diag included)
#pragma unroll
        for (int e = 0; e < DH; e++) out[e] = fmaf(a, Vs[j][e], out[e]);
    }
#pragma unroll
    for (int d = 0; d < DH; d++) {
        float qd = q[d];
#pragma unroll
        for (int e = 0; e < DH; e++) out[e] = fmaf(qd, Ss[d][e], out[e]);
    }

    int t_ = c * CHUNKSZ + tid;
    float z = Z[(size_t)bh * SEQ + t_];
    ushort_t* op = A + (((size_t)(b_ * SEQ + t_)) * NH + h_) * DH;
#pragma unroll
    for (int e = 0; e < DH; e++) op[e] = f2bf(out[e] * z);
}

// ---------------------------------------------------------------------------
extern "C" void kernel_launch(void* const* d_in, const int* in_sizes, int n_in,
                              void* d_out, int out_size, void* d_ws, size_t ws_size,
                              hipStream_t stream)
{
    const float* x  = (const float*)d_in[0];
    const float* Wq = (const float*)d_in[1];
    const float* Wk = (const float*)d_in[2];
    const float* Wv = (const float*)d_in[3];
    const float* Wo = (const float*)d_in[4];
    const float* bo = (const float*)d_in[5];
    float* out = (float*)d_out;

    const size_t NEL = (size_t)BATCH * SEQ * DMODEL;   // 16,777,216
    ushort_t* Qb = (ushort_t*)d_ws;
    ushort_t* Kb = Qb + NEL;
    ushort_t* Vb = Kb + NEL;
    ushort_t* Ab = Vb + NEL;
    float*    Zb = (float*)(Ab + NEL);                  // B*H*T floats
    float*    Sl = Zb + (size_t)BATCH * NH * SEQ;       // 64*32*64*64 floats
    // workspace use: 4*NEL*2 + 1MB + 32MB ~= 161 MB

    const int M = BATCH * SEQ;
    dim3 gg(M / BM, DMODEL / BN);

    gemm_k<0><<<gg, dim3(256), 0, stream>>>(x, Wq, nullptr, Qb, M, DMODEL, DMODEL);
    gemm_k<0><<<gg, dim3(256), 0, stream>>>(x, Wk, nullptr, Kb, M, DMODEL, DMODEL);
    gemm_k<1><<<gg, dim3(256), 0, stream>>>(x, Wv, nullptr, Vb, M, DMODEL, DMODEL);

    z_k<<<dim3(BATCH * SEQ), dim3(64), 0, stream>>>(Qb, Kb, Zb);

    kv_k<<<dim3(BATCH * NH * NCHUNK), dim3(256), 0, stream>>>(Kb, Vb, Sl);
    scan_k<<<dim3(BATCH * NH), dim3(256), 0, stream>>>(Sl);
    attn_k<<<dim3(BATCH * NH * NCHUNK), dim3(128), 0, stream>>>(Qb, Kb, Vb, Sl, Zb, Ab);

    gemm_k<2><<<gg, dim3(256), 0, stream>>>(Ab, Wo, bo, out, M, DMODEL, DMODEL);
}

// Round 2
// 692.566 us; speedup vs baseline: 2.8245x; 2.8245x over previous
//
#include <hip/hip_runtime.h>
#include <hip/hip_bf16.h>

#define BATCH 4
#define SEQ   4096
#define DMODEL 1024
#define NH    16
#define DH    64
#define NCHUNK 32
#define CHUNKSZ 128
#define FEPS  1e-6f

typedef unsigned short ushort_t;
typedef __attribute__((ext_vector_type(8))) short short8;
typedef __attribute__((ext_vector_type(4))) float f32x4;

__device__ __forceinline__ float bf2f(ushort_t u) {
    union { unsigned int i; float f; } x; x.i = ((unsigned int)u) << 16; return x.f;
}
__device__ __forceinline__ ushort_t f2bf(float f) {
    union { float f; unsigned int i; } x; x.f = f;
    unsigned int lsb = (x.i >> 16) & 1u;
    x.i += 0x7fffu + lsb;   // round-to-nearest-even
    return (ushort_t)(x.i >> 16);
}

__device__ __forceinline__ void load_lds16(const void* g, void* l) {
    __builtin_amdgcn_global_load_lds(
        (const __attribute__((address_space(1))) int*)g,
        (__attribute__((address_space(3))) int*)l, 16, 0, 0);
}

// ---------------------------------------------------------------------------
// x f32 -> bf16 (same layout)
// ---------------------------------------------------------------------------
__global__ __launch_bounds__(256) void cvt_k(const float* __restrict__ X,
                                             ushort_t* __restrict__ Xb, int n4)
{
    int i = blockIdx.x * blockDim.x + threadIdx.x;
    int stride = gridDim.x * blockDim.x;
    for (; i < n4; i += stride) {
        float4 v = ((const float4*)X)[i];
        ushort4 u;
        u.x = f2bf(v.x); u.y = f2bf(v.y); u.z = f2bf(v.z); u.w = f2bf(v.w);
        ((ushort4*)Xb)[i] = u;
    }
}

// ---------------------------------------------------------------------------
// W f32 [K,N] -> WT bf16 [N,K]   (WT[n][k] = W[k][n]) via 32x32 LDS tiles
// ---------------------------------------------------------------------------
__global__ __launch_bounds__(256) void wt_k(const float* __restrict__ W,
                                            ushort_t* __restrict__ WT)
{
    __shared__ float tile[32][33];
    int tx = threadIdx.x & 31, ty = threadIdx.x >> 5;
    int kb = blockIdx.x << 5, nb = blockIdx.y << 5;
#pragma unroll
    for (int i = 0; i < 4; i++)
        tile[ty + i * 8][tx] = W[(size_t)(kb + ty + i * 8) * DMODEL + nb + tx];
    __syncthreads();
#pragma unroll
    for (int i = 0; i < 4; i++)
        WT[(size_t)(nb + ty + i * 8) * DMODEL + kb + tx] = f2bf(tile[tx][ty + i * 8]);
}

// ---------------------------------------------------------------------------
// MFMA GEMM: C = op(A @ Bt^T). A [M,K] bf16 row-major, Bt [N,K] bf16 row-major.
// 128x128 tile, BK=32, 4 waves (2x2), 16x16x32 bf16 MFMA, global_load_lds w16.
// LDS layout [kchunk][row][8] -> conflict-free ds_read_b128 fragment loads.
// MODE 0: feature(elu+1), bf16 scatter to [b,h,t,d]
// MODE 1: plain, bf16 scatter to [b,h,t,d]
// MODE 2: +bias, f32 row-major [M,N]
// ---------------------------------------------------------------------------
#define GBM 128
#define GBN 128
#define GBK 32

template<int MODE>
__global__ __launch_bounds__(256) void mgemm_k(const ushort_t* __restrict__ Ap,
                                               const ushort_t* __restrict__ Bt,
                                               const float* __restrict__ bias,
                                               void* __restrict__ Cp,
                                               int M, int N, int K)
{
    __shared__ short smem[8192];      // As [4][128][8] | Bs [4][128][8]
    short* As = smem;
    short* Bs = smem + 4096;
    const int tid = threadIdx.x;
    const int l  = tid & 63;
    const int w  = tid >> 6;
    const int wm = w >> 1, wn = w & 1;
    const int lr = l & 15;            // row/col within 16x16 fragment
    const int kc = l >> 4;            // k-chunk of 8

    const size_t m0 = (size_t)blockIdx.x * GBM;
    const size_t n0 = (size_t)blockIdx.y * GBN;

    f32x4 acc[4][4];
#pragma unroll
    for (int i = 0; i < 4; i++)
#pragma unroll
        for (int j = 0; j < 4; j++) acc[i][j] = (f32x4){0.f, 0.f, 0.f, 0.f};

    // staging segments for this wave: s = 2w+i ; kchunk = s>>1, row-half = s&1
    const int s0 = w * 2;

    for (int k0 = 0; k0 < K; k0 += GBK) {
#pragma unroll
        for (int i = 0; i < 2; i++) {
            const int s   = s0 + i;
            const int kch = s >> 1;
            const int rh  = (s & 1) << 6;
            const int ldsoff = (kch * 128 + rh) * 8;          // shorts
            load_lds16(Ap + (m0 + rh + l) * K + k0 + kch * 8, As + ldsoff);
            load_lds16(Bt + (n0 + rh + l) * K + k0 + kch * 8, Bs + ldsoff);
        }
        __syncthreads();
        short8 af[4], bfr[4];
#pragma unroll
        for (int t = 0; t < 4; t++) {
            af[t]  = *(const short8*)(As + (kc * 128 + wm * 64 + t * 16 + lr) * 8);
            bfr[t] = *(const short8*)(Bs + (kc * 128 + wn * 64 + t * 16 + lr) * 8);
        }
#pragma unroll
        for (int mt = 0; mt < 4; mt++)
#pragma unroll
            for (int nt = 0; nt < 4; nt++)
                acc[mt][nt] = __builtin_amdgcn_mfma_f32_16x16x32_bf16(
                    af[mt], bfr[nt], acc[mt][nt], 0, 0, 0);
        __syncthreads();
    }

    // epilogue: C row = m0 + wm*64 + mt*16 + (l>>4)*4 + j ; col = n0 + wn*64 + nt*16 + lr
#pragma unroll
    for (int mt = 0; mt < 4; mt++) {
#pragma unroll
        for (int nt = 0; nt < 4; nt++) {
#pragma unroll
            for (int j = 0; j < 4; j++) {
                int m = (int)m0 + wm * 64 + mt * 16 + (l >> 4) * 4 + j;
                int n = (int)n0 + wn * 64 + nt * 16 + lr;
                float v = acc[mt][nt][j];
                if (MODE == 2) {
                    ((float*)Cp)[(size_t)m * N + n] = v + bias[n];
                } else {
                    if (MODE == 0) v = (v > 0.f) ? (v + 1.f) : __expf(v);
                    int b_ = m >> 12, t_ = m & 4095, h_ = n >> 6, d_ = n & 63;
                    ((ushort_t*)Cp)[((((size_t)b_ * NH + h_) * SEQ + t_) << 6) + d_] = f2bf(v);
                }
            }
        }
    }
}

// ---------------------------------------------------------------------------
// Z[b,h,t] = 1/(sum_d Q[b,h,t,d] * cumsum_{h'<=h} K[b,h',t,d] + eps)
// ---------------------------------------------------------------------------
__global__ __launch_bounds__(64) void z_k(const ushort_t* __restrict__ Q,
                                          const ushort_t* __restrict__ K,
                                          float* __restrict__ Z)
{
    int bt = blockIdx.x;
    int b_ = bt >> 12, t_ = bt & 4095;
    int d = threadIdx.x;
    float ck = 0.f;
    for (int h = 0; h < NH; h++) {
        size_t idx = ((((size_t)b_ * NH + h) * SEQ + t_) << 6) + d;
        ck += bf2f(K[idx]);
        float p = bf2f(Q[idx]) * ck;
#pragma unroll
        for (int off = 32; off; off >>= 1) p += __shfl_down(p, off, 64);
        if (d == 0) Z[((size_t)b_ * NH + h) * SEQ + t_] = 1.f / (p + FEPS);
    }
}

// ---------------------------------------------------------------------------
// Per-chunk S_local[b,h,c] = K_c^T V_c
// ---------------------------------------------------------------------------
__global__ __launch_bounds__(256) void kv_k(const ushort_t* __restrict__ Kf,
                                            const ushort_t* __restrict__ Vf,
                                            float* __restrict__ Sloc)
{
    int blk = blockIdx.x;
    int c  = blk & (NCHUNK - 1);
    int bh = blk >> 5;
    size_t rowbase = ((size_t)bh * SEQ + (size_t)c * CHUNKSZ) * DH;
    const ushort4* K4 = (const ushort4*)(Kf + rowbase);
    const ushort4* V4 = (const ushort4*)(Vf + rowbase);
    __shared__ float Ks[CHUNKSZ][DH];
    __shared__ float Vs[CHUNKSZ][DH];
    int tid = threadIdx.x;
#pragma unroll
    for (int i = 0; i < 8; i++) {
        int idx = tid + i * 256;
        ushort4 uk = K4[idx], uv = V4[idx];
        ((float4*)Ks)[idx] = make_float4(bf2f(uk.x), bf2f(uk.y), bf2f(uk.z), bf2f(uk.w));
        ((float4*)Vs)[idx] = make_float4(bf2f(uv.x), bf2f(uv.y), bf2f(uv.z), bf2f(uv.w));
    }
    __syncthreads();
    int d  = tid >> 2;
    int e0 = (tid & 3) << 4;
    float acc[16];
#pragma unroll
    for (int e = 0; e < 16; e++) acc[e] = 0.f;
    for (int j = 0; j < CHUNKSZ; j++) {
        float kv = Ks[j][d];
#pragma unroll
        for (int e = 0; e < 16; e++) acc[e] = fmaf(kv, Vs[j][e0 + e], acc[e]);
    }
    float* out = Sloc + (size_t)blk * DH * DH + d * DH + e0;
#pragma unroll
    for (int e = 0; e < 16; e++) out[e] = acc[e];
}

// ---------------------------------------------------------------------------
// Exclusive prefix over chunks (in place)
// ---------------------------------------------------------------------------
__global__ __launch_bounds__(256) void scan_k(float* __restrict__ Sloc)
{
    int bh = blockIdx.x;
    int tid = threadIdx.x;
    float* base = Sloc + (size_t)bh * NCHUNK * DH * DH;
    float acc[16];
#pragma unroll
    for (int i = 0; i < 16; i++) acc[i] = 0.f;
    for (int cc = 0; cc < NCHUNK; cc++) {
        float* p = base + (size_t)cc * DH * DH;
#pragma unroll
        for (int i = 0; i < 16; i++) {
            int idx = tid + i * 256;
            float tmp = p[idx];
            p[idx] = acc[i];
            acc[i] += tmp;
        }
    }
}

// ---------------------------------------------------------------------------
// Per-chunk output: out = (tril(Q K^T)) V + Q S_pre, scaled by Z -> bf16 A
// ---------------------------------------------------------------------------
__global__ __launch_bounds__(128) void attn_k(const ushort_t* __restrict__ Qf,
                                              const ushort_t* __restrict__ Kf,
                                              const ushort_t* __restrict__ Vf,
                                              const float* __restrict__ Sloc,
                                              const float* __restrict__ Z,
                                              ushort_t* __restrict__ A)
{
    int blk = blockIdx.x;
    int c  = blk & (NCHUNK - 1);
    int bh = blk >> 5;
    int b_ = bh >> 4, h_ = bh & 15;
    size_t rowbase = ((size_t)bh * SEQ + (size_t)c * CHUNKSZ) * DH;
    const ushort4* K4 = (const ushort4*)(Kf + rowbase);
    const ushort4* V4 = (const ushort4*)(Vf + rowbase);
    const float4*  S4 = (const float4*)(Sloc + (size_t)blk * DH * DH);
    __shared__ float Ks[CHUNKSZ][DH];
    __shared__ float Vs[CHUNKSZ][DH];
    __shared__ float Ss[DH][DH];
    int tid = threadIdx.x;
#pragma unroll
    for (int i = 0; i < 16; i++) {
        int idx = tid + i * 128;
        ushort4 uk = K4[idx], uv = V4[idx];
        ((float4*)Ks)[idx] = make_float4(bf2f(uk.x), bf2f(uk.y), bf2f(uk.z), bf2f(uk.w));
        ((float4*)Vs)[idx] = make_float4(bf2f(uv.x), bf2f(uv.y), bf2f(uv.z), bf2f(uv.w));
    }
#pragma unroll
    for (int i = 0; i < 8; i++) {
        int idx = tid + i * 128;
        ((float4*)Ss)[idx] = S4[idx];
    }
    float q[DH];
    {
        const ushort4* Q4 = (const ushort4*)(Qf + rowbase + (size_t)tid * DH);
#pragma unroll
        for (int d4 = 0; d4 < 16; d4++) {
            ushort4 u = Q4[d4];
            q[d4 * 4 + 0] = bf2f(u.x); q[d4 * 4 + 1] = bf2f(u.y);
            q[d4 * 4 + 2] = bf2f(u.z); q[d4 * 4 + 3] = bf2f(u.w);
        }
    }
    __syncthreads();

    float out[DH];
#pragma unroll
    for (int e = 0; e < DH; e++) out[e] = 0.f;

    for (int j = 0; j < CHUNKSZ; j++) {
        float a = 0.f;
#pragma unroll
        for (int d = 0; d < DH; d++) a = fmaf(q[d], Ks[j][d], a);
        a = (j <= tid) ? a : 0.f;
#pragma unroll
        for (int e = 0; e < DH; e++) out[e] = fmaf(a, Vs[j][e], out[e]);
    }
#pragma unroll
    for (int d = 0; d < DH; d++) {
        float qd = q[d];
#pragma unroll
        for (int e = 0; e < DH; e++) out[e] = fmaf(qd, Ss[d][e], out[e]);
    }

    int t_ = c * CHUNKSZ + tid;
    float z = Z[(size_t)bh * SEQ + t_];
    ushort_t* op = A + (((size_t)(b_ * SEQ + t_)) * NH + h_) * DH;
#pragma unroll
    for (int e = 0; e < DH; e++) op[e] = f2bf(out[e] * z);
}

// ---------------------------------------------------------------------------
extern "C" void kernel_launch(void* const* d_in, const int* in_sizes, int n_in,
                              void* d_out, int out_size, void* d_ws, size_t ws_size,
                              hipStream_t stream)
{
    const float* x  = (const float*)d_in[0];
    const float* Wq = (const float*)d_in[1];
    const float* Wk = (const float*)d_in[2];
    const float* Wv = (const float*)d_in[3];
    const float* Wo = (const float*)d_in[4];
    const float* bo = (const float*)d_in[5];
    float* out = (float*)d_out;

    const size_t NEL = (size_t)BATCH * SEQ * DMODEL;   // 16,777,216
    const size_t WEL = (size_t)DMODEL * DMODEL;        // 1,048,576
    ushort_t* Qb  = (ushort_t*)d_ws;
    ushort_t* Kb  = Qb + NEL;
    ushort_t* Vb  = Kb + NEL;
    ushort_t* XAb = Vb + NEL;                          // x bf16, later attn out
    float*    Zb  = (float*)(XAb + NEL);               // B*H*T floats (1MB)
    ushort_t* WTq = (ushort_t*)(Zb + (size_t)BATCH * NH * SEQ);
    ushort_t* WTk = WTq + WEL;
    ushort_t* WTv = WTk + WEL;
    ushort_t* WTo = WTv + WEL;
    float*    Sl  = (float*)d_out;                     // scratch; final gemm overwrites
    // ws use: 4*NEL*2 + 1MB + 4*WEL*2 = ~143.5 MB

    const int M = BATCH * SEQ;
    dim3 gw(32, 32);
    dim3 gg(M / GBM, DMODEL / GBN);

    cvt_k<<<dim3(2048), dim3(256), 0, stream>>>(x, XAb, (int)(NEL / 4));
    wt_k<<<gw, dim3(256), 0, stream>>>(Wq, WTq);
    wt_k<<<gw, dim3(256), 0, stream>>>(Wk, WTk);
    wt_k<<<gw, dim3(256), 0, stream>>>(Wv, WTv);
    wt_k<<<gw, dim3(256), 0, stream>>>(Wo, WTo);

    mgemm_k<0><<<gg, dim3(256), 0, stream>>>(XAb, WTq, nullptr, Qb, M, DMODEL, DMODEL);
    mgemm_k<0><<<gg, dim3(256), 0, stream>>>(XAb, WTk, nullptr, Kb, M, DMODEL, DMODEL);
    mgemm_k<1><<<gg, dim3(256), 0, stream>>>(XAb, WTv, nullptr, Vb, M, DMODEL, DMODEL);

    z_k<<<dim3(BATCH * SEQ), dim3(64), 0, stream>>>(Qb, Kb, Zb);

    kv_k<<<dim3(BATCH * NH * NCHUNK), dim3(256), 0, stream>>>(Kb, Vb, Sl);
    scan_k<<<dim3(BATCH * NH), dim3(256), 0, stream>>>(Sl);
    attn_k<<<dim3(BATCH * NH * NCHUNK), dim3(128), 0, stream>>>(Qb, Kb, Vb, Sl, Zb, XAb);

    mgemm_k<2><<<gg, dim3(256), 0, stream>>>(XAb, WTo, bo, out, M, DMODEL, DMODEL);
}

// Round 3
// 445.175 us; speedup vs baseline: 4.3941x; 1.5557x over previous
//
#include <hip/hip_runtime.h>
#include <hip/hip_bf16.h>

#define BATCH 4
#define SEQ   4096
#define DMODEL 1024
#define NH    16
#define DH    64
#define NCHUNK 32
#define CHUNKSZ 128
#define FEPS  1e-6f

typedef unsigned short ushort_t;
typedef __attribute__((ext_vector_type(8))) short short8;
typedef __attribute__((ext_vector_type(4))) float f32x4;

__device__ __forceinline__ float bf2f(ushort_t u) {
    union { unsigned int i; float f; } x; x.i = ((unsigned int)u) << 16; return x.f;
}
__device__ __forceinline__ ushort_t f2bf(float f) {
    union { float f; unsigned int i; } x; x.f = f;
    unsigned int lsb = (x.i >> 16) & 1u;
    x.i += 0x7fffu + lsb;   // round-to-nearest-even
    return (ushort_t)(x.i >> 16);
}

__device__ __forceinline__ void load_lds16(const void* g, void* l) {
    __builtin_amdgcn_global_load_lds(
        (const __attribute__((address_space(1))) int*)g,
        (__attribute__((address_space(3))) int*)l, 16, 0, 0);
}

// ---------------------------------------------------------------------------
// x f32 -> bf16 (same layout)
// ---------------------------------------------------------------------------
__global__ __launch_bounds__(256) void cvt_k(const float* __restrict__ X,
                                             ushort_t* __restrict__ Xb, int n4)
{
    int i = blockIdx.x * blockDim.x + threadIdx.x;
    int stride = gridDim.x * blockDim.x;
    for (; i < n4; i += stride) {
        float4 v = ((const float4*)X)[i];
        ushort4 u;
        u.x = f2bf(v.x); u.y = f2bf(v.y); u.z = f2bf(v.z); u.w = f2bf(v.w);
        ((ushort4*)Xb)[i] = u;
    }
}

// ---------------------------------------------------------------------------
// W f32 [K,N] -> WT bf16 [N,K]
// ---------------------------------------------------------------------------
__global__ __launch_bounds__(256) void wt_k(const float* __restrict__ W,
                                            ushort_t* __restrict__ WT)
{
    __shared__ float tile[32][33];
    int tx = threadIdx.x & 31, ty = threadIdx.x >> 5;
    int kb = blockIdx.x << 5, nb = blockIdx.y << 5;
#pragma unroll
    for (int i = 0; i < 4; i++)
        tile[ty + i * 8][tx] = W[(size_t)(kb + ty + i * 8) * DMODEL + nb + tx];
    __syncthreads();
#pragma unroll
    for (int i = 0; i < 4; i++)
        WT[(size_t)(nb + ty + i * 8) * DMODEL + kb + tx] = f2bf(tile[tx][ty + i * 8]);
}

// ---------------------------------------------------------------------------
// MFMA GEMM (128x128 tile, BK=32) — unchanged from round 2 (validated)
// ---------------------------------------------------------------------------
#define GBM 128
#define GBN 128
#define GBK 32

template<int MODE>
__global__ __launch_bounds__(256) void mgemm_k(const ushort_t* __restrict__ Ap,
                                               const ushort_t* __restrict__ Bt,
                                               const float* __restrict__ bias,
                                               void* __restrict__ Cp,
                                               int M, int N, int K)
{
    __shared__ short smem[8192];
    short* As = smem;
    short* Bs = smem + 4096;
    const int tid = threadIdx.x;
    const int l  = tid & 63;
    const int w  = tid >> 6;
    const int wm = w >> 1, wn = w & 1;
    const int lr = l & 15;
    const int kc = l >> 4;

    const size_t m0 = (size_t)blockIdx.x * GBM;
    const size_t n0 = (size_t)blockIdx.y * GBN;

    f32x4 acc[4][4];
#pragma unroll
    for (int i = 0; i < 4; i++)
#pragma unroll
        for (int j = 0; j < 4; j++) acc[i][j] = (f32x4){0.f, 0.f, 0.f, 0.f};

    const int s0 = w * 2;

    for (int k0 = 0; k0 < K; k0 += GBK) {
#pragma unroll
        for (int i = 0; i < 2; i++) {
            const int s   = s0 + i;
            const int kch = s >> 1;
            const int rh  = (s & 1) << 6;
            const int ldsoff = (kch * 128 + rh) * 8;
            load_lds16(Ap + (m0 + rh + l) * K + k0 + kch * 8, As + ldsoff);
            load_lds16(Bt + (n0 + rh + l) * K + k0 + kch * 8, Bs + ldsoff);
        }
        __syncthreads();
        short8 af[4], bfr[4];
#pragma unroll
        for (int t = 0; t < 4; t++) {
            af[t]  = *(const short8*)(As + (kc * 128 + wm * 64 + t * 16 + lr) * 8);
            bfr[t] = *(const short8*)(Bs + (kc * 128 + wn * 64 + t * 16 + lr) * 8);
        }
#pragma unroll
        for (int mt = 0; mt < 4; mt++)
#pragma unroll
            for (int nt = 0; nt < 4; nt++)
                acc[mt][nt] = __builtin_amdgcn_mfma_f32_16x16x32_bf16(
                    af[mt], bfr[nt], acc[mt][nt], 0, 0, 0);
        __syncthreads();
    }

#pragma unroll
    for (int mt = 0; mt < 4; mt++) {
#pragma unroll
        for (int nt = 0; nt < 4; nt++) {
#pragma unroll
            for (int j = 0; j < 4; j++) {
                int m = (int)m0 + wm * 64 + mt * 16 + (l >> 4) * 4 + j;
                int n = (int)n0 + wn * 64 + nt * 16 + lr;
                float v = acc[mt][nt][j];
                if (MODE == 2) {
                    ((float*)Cp)[(size_t)m * N + n] = v + bias[n];
                } else {
                    if (MODE == 0) v = (v > 0.f) ? (v + 1.f) : __expf(v);
                    int b_ = m >> 12, t_ = m & 4095, h_ = n >> 6, d_ = n & 63;
                    ((ushort_t*)Cp)[((((size_t)b_ * NH + h_) * SEQ + t_) << 6) + d_] = f2bf(v);
                }
            }
        }
    }
}

// ---------------------------------------------------------------------------
// Z[b,h,t] = 1/(sum_d Q[b,h,t,d] * cumsum_{h'<=h} K[b,h',t,d] + eps)
// prefetch all heads, then serial reduce chain
// ---------------------------------------------------------------------------
__global__ __launch_bounds__(64) void z_k(const ushort_t* __restrict__ Q,
                                          const ushort_t* __restrict__ K,
                                          float* __restrict__ Z)
{
    int bt = blockIdx.x;
    int b_ = bt >> 12, t_ = bt & 4095;
    int d = threadIdx.x;
    float qv[NH], kv[NH];
    size_t base = (((size_t)b_ * NH) * SEQ + t_) * DH + d;
#pragma unroll
    for (int h = 0; h < NH; h++) {
        qv[h] = bf2f(Q[base + (size_t)h * SEQ * DH]);
        kv[h] = bf2f(K[base + (size_t)h * SEQ * DH]);
    }
    float ck = 0.f;
#pragma unroll
    for (int h = 0; h < NH; h++) {
        ck += kv[h];
        float p = qv[h] * ck;
#pragma unroll
        for (int off = 1; off < 64; off <<= 1) p += __shfl_xor(p, off, 64);
        if (d == 0) Z[((size_t)b_ * NH + h) * SEQ + t_] = 1.f / (p + FEPS);
    }
}

// ---------------------------------------------------------------------------
// Per-chunk S_local = K_c^T V_c  via MFMA. KT/VT staged transposed in LDS.
// ---------------------------------------------------------------------------
__global__ __launch_bounds__(256) void kv_k(const ushort_t* __restrict__ Kf,
                                            const ushort_t* __restrict__ Vf,
                                            float* __restrict__ Sloc)
{
    __shared__ short KTs[8192];   // [16 kc(j)][64 d][8 j-in-chunk]
    __shared__ short VTs[8192];   // [16 kc(j)][64 e][8]
    const int tid = threadIdx.x;
    const int l = tid & 63, w = tid >> 6;
    const int lr = l & 15, hi = l >> 4;
    const int blk = blockIdx.x;
    const size_t rowbase = ((size_t)(blk >> 5) * SEQ + (size_t)(blk & 31) * CHUNKSZ) * DH;
    const uint4* K16 = (const uint4*)(Kf + rowbase);
    const uint4* V16 = (const uint4*)(Vf + rowbase);
#pragma unroll
    for (int i = 0; i < 4; i++) {
        int idx = tid + i * 256;               // 1024 x 16B = 128x64 bf16
        union { uint4 q; ushort_t us[8]; } kk, vv;
        kk.q = K16[idx]; vv.q = V16[idx];
        int j = idx >> 3, e0 = (idx & 7) << 3;
#pragma unroll
        for (int s = 0; s < 8; s++) {
            int off = ((j >> 3) * 64 + e0 + s) * 8 + (j & 7);
            KTs[off] = (short)kk.us[s];
            VTs[off] = (short)vv.us[s];
        }
    }
    __syncthreads();
    f32x4 acc[4];
#pragma unroll
    for (int nt = 0; nt < 4; nt++) acc[nt] = (f32x4){0.f, 0.f, 0.f, 0.f};
#pragma unroll
    for (int ks = 0; ks < 4; ks++) {
        short8 af = *(const short8*)(KTs + ((ks * 4 + hi) * 64 + w * 16 + lr) * 8);
        short8 bf[4];
#pragma unroll
        for (int nt = 0; nt < 4; nt++)
            bf[nt] = *(const short8*)(VTs + ((ks * 4 + hi) * 64 + nt * 16 + lr) * 8);
#pragma unroll
        for (int nt = 0; nt < 4; nt++)
            acc[nt] = __builtin_amdgcn_mfma_f32_16x16x32_bf16(af, bf[nt], acc[nt], 0, 0, 0);
    }
    float* outp = Sloc + (size_t)blk * DH * DH;
#pragma unroll
    for (int nt = 0; nt < 4; nt++)
#pragma unroll
        for (int jr = 0; jr < 4; jr++) {
            int d_ = w * 16 + hi * 4 + jr;
            int e_ = nt * 16 + lr;
            outp[d_ * DH + e_] = acc[nt][jr];
        }
}

// ---------------------------------------------------------------------------
// Exclusive prefix over chunks, element-parallel: block (bh, seg of 256 elems)
// ---------------------------------------------------------------------------
__global__ __launch_bounds__(256) void scan_k(float* __restrict__ Sloc)
{
    int bh = blockIdx.x, seg = blockIdx.y;
    int e = seg * 256 + threadIdx.x;
    float* base = Sloc + (size_t)bh * NCHUNK * DH * DH + e;
    float acc = 0.f;
    float cur = base[0];
    for (int cc = 0; cc < NCHUNK; cc++) {
        float nxt = (cc + 1 < NCHUNK) ? base[(size_t)(cc + 1) * DH * DH] : 0.f;
        base[(size_t)cc * DH * DH] = acc;
        acc += cur;
        cur = nxt;
    }
}

// ---------------------------------------------------------------------------
// MFMA attention chunk kernel: out = (tril(Q K^T)) V + Q S_pre, scaled by Z.
// 4 waves; wave w owns output rows [w*32, w*32+32).
// LDS (shorts): Qs[8][128][8] | Ks[8][128][8] (P[16][128][8] overlays) |
//               VTs[16][64][8] | STs[8][64][8]   = 72 KB -> 2 blocks/CU
// ---------------------------------------------------------------------------
__global__ __launch_bounds__(256) void attn_k(const ushort_t* __restrict__ Qf,
                                              const ushort_t* __restrict__ Kf,
                                              const ushort_t* __restrict__ Vf,
                                              const float* __restrict__ Sloc,
                                              const float* __restrict__ Z,
                                              ushort_t* __restrict__ A)
{
    __shared__ short smem[36864];
    short* Qs  = smem;            // [8][128][8]
    short* Ks  = smem + 8192;     // [8][128][8]
    short* Ps  = smem + 8192;     // [16][128][8] (reuses Ks + 16KB more)
    short* VTs = smem + 24576;    // [16][64][8]
    short* STs = smem + 32768;    // [8][64][8]

    const int tid = threadIdx.x;
    const int l = tid & 63, w = tid >> 6;
    const int lr = l & 15, hi = l >> 4;
    const int blk = blockIdx.x;
    const int c = blk & (NCHUNK - 1), bh = blk >> 5;
    const int b_ = bh >> 4, h_ = bh & 15;
    const size_t rowbase = ((size_t)bh * SEQ + (size_t)c * CHUNKSZ) * DH;

    // stage Q, K: [kc][row][8] via global_load_lds (4 issues x 2 tensors per wave)
#pragma unroll
    for (int ii = 0; ii < 4; ii++) {
        int s = w * 4 + ii;
        int kc = s >> 1, rh = (s & 1) << 6;
        int ldso = (kc * 128 + rh) * 8;
        load_lds16(Qf + rowbase + (size_t)(rh + l) * DH + kc * 8, Qs + ldso);
        load_lds16(Kf + rowbase + (size_t)(rh + l) * DH + kc * 8, Ks + ldso);
    }
    // stage V^T (reg -> scalar LDS writes)
    {
        const uint4* V16 = (const uint4*)(Vf + rowbase);
#pragma unroll
        for (int i = 0; i < 4; i++) {
            int idx = tid + i * 256;
            union { uint4 q; ushort_t us[8]; } vv;
            vv.q = V16[idx];
            int j = idx >> 3, e0 = (idx & 7) << 3;
#pragma unroll
            for (int s = 0; s < 8; s++)
                VTs[((j >> 3) * 64 + e0 + s) * 8 + (j & 7)] = (short)vv.us[s];
        }
    }
    // stage S_pre^T as bf16
    {
        const float4* S16 = (const float4*)(Sloc + (size_t)blk * DH * DH);
#pragma unroll
        for (int i = 0; i < 4; i++) {
            int idx = tid + i * 256;
            float4 f = S16[idx];
            int d = idx >> 4, e0 = (idx & 15) << 2;
            STs[((d >> 3) * 64 + e0 + 0) * 8 + (d & 7)] = (short)f2bf(f.x);
            STs[((d >> 3) * 64 + e0 + 1) * 8 + (d & 7)] = (short)f2bf(f.y);
            STs[((d >> 3) * 64 + e0 + 2) * 8 + (d & 7)] = (short)f2bf(f.z);
            STs[((d >> 3) * 64 + e0 + 3) * 8 + (d & 7)] = (short)f2bf(f.w);
        }
    }
    __syncthreads();

    // phase 1: S = Q K^T, rows [w*32, w*32+32), all 128 cols
    f32x4 acc1[2][8];
#pragma unroll
    for (int mt = 0; mt < 2; mt++)
#pragma unroll
        for (int nt = 0; nt < 8; nt++) acc1[mt][nt] = (f32x4){0.f, 0.f, 0.f, 0.f};
#pragma unroll
    for (int ks = 0; ks < 2; ks++) {
        short8 af[2], bf[8];
#pragma unroll
        for (int mt = 0; mt < 2; mt++)
            af[mt] = *(const short8*)(Qs + ((ks * 4 + hi) * 128 + w * 32 + mt * 16 + lr) * 8);
#pragma unroll
        for (int nt = 0; nt < 8; nt++)
            bf[nt] = *(const short8*)(Ks + ((ks * 4 + hi) * 128 + nt * 16 + lr) * 8);
#pragma unroll
        for (int mt = 0; mt < 2; mt++)
#pragma unroll
            for (int nt = 0; nt < 8; nt++)
                acc1[mt][nt] = __builtin_amdgcn_mfma_f32_16x16x32_bf16(
                    af[mt], bf[nt], acc1[mt][nt], 0, 0, 0);
    }
    __syncthreads();   // all waves done reading Ks before P overwrites it

    // phase 2: causal mask + P -> bf16 LDS in A-fragment layout
#pragma unroll
    for (int mt = 0; mt < 2; mt++)
#pragma unroll
        for (int nt = 0; nt < 8; nt++)
#pragma unroll
            for (int jr = 0; jr < 4; jr++) {
                int i_ = w * 32 + mt * 16 + hi * 4 + jr;
                int j_ = nt * 16 + lr;
                float v = (j_ <= i_) ? acc1[mt][nt][jr] : 0.f;
                Ps[((j_ >> 3) * 128 + i_) * 8 + (j_ & 7)] = (short)f2bf(v);
            }
    __syncthreads();

    // phase 3: out = P V   (K=128)
    f32x4 acc2[2][4];
#pragma unroll
    for (int mt = 0; mt < 2; mt++)
#pragma unroll
        for (int nt = 0; nt < 4; nt++) acc2[mt][nt] = (f32x4){0.f, 0.f, 0.f, 0.f};
#pragma unroll
    for (int ks = 0; ks < 4; ks++) {
        short8 af[2], bf[4];
#pragma unroll
        for (int mt = 0; mt < 2; mt++)
            af[mt] = *(const short8*)(Ps + ((ks * 4 + hi) * 128 + w * 32 + mt * 16 + lr) * 8);
#pragma unroll
        for (int nt = 0; nt < 4; nt++)
            bf[nt] = *(const short8*)(VTs + ((ks * 4 + hi) * 64 + nt * 16 + lr) * 8);
#pragma unroll
        for (int mt = 0; mt < 2; mt++)
#pragma unroll
            for (int nt = 0; nt < 4; nt++)
                acc2[mt][nt] = __builtin_amdgcn_mfma_f32_16x16x32_bf16(
                    af[mt], bf[nt], acc2[mt][nt], 0, 0, 0);
    }
    // phase 4: out += Q S_pre  (K=64)
#pragma unroll
    for (int ks = 0; ks < 2; ks++) {
        short8 af[2], bf[4];
#pragma unroll
        for (int mt = 0; mt < 2; mt++)
            af[mt] = *(const short8*)(Qs + ((ks * 4 + hi) * 128 + w * 32 + mt * 16 + lr) * 8);
#pragma unroll
        for (int nt = 0; nt < 4; nt++)
            bf[nt] = *(const short8*)(STs + ((ks * 4 + hi) * 64 + nt * 16 + lr) * 8);
#pragma unroll
        for (int mt = 0; mt < 2; mt++)
#pragma unroll
            for (int nt = 0; nt < 4; nt++)
                acc2[mt][nt] = __builtin_amdgcn_mfma_f32_16x16x32_bf16(
                    af[mt], bf[nt], acc2[mt][nt], 0, 0, 0);
    }

    // epilogue: scale by Z, scatter bf16 to [ (b*T+t) , h*64+e ]
#pragma unroll
    for (int mt = 0; mt < 2; mt++) {
#pragma unroll
        for (int jr = 0; jr < 4; jr++) {
            int i_ = w * 32 + mt * 16 + hi * 4 + jr;
            int t_ = c * CHUNKSZ + i_;
            float z = Z[(size_t)bh * SEQ + t_];
            ushort_t* op = A + (((size_t)(b_ * SEQ + t_)) * NH + h_) * DH;
#pragma unroll
            for (int nt = 0; nt < 4; nt++)
                op[nt * 16 + lr] = f2bf(acc2[mt][nt][jr] * z);
        }
    }
}

// ---------------------------------------------------------------------------
extern "C" void kernel_launch(void* const* d_in, const int* in_sizes, int n_in,
                              void* d_out, int out_size, void* d_ws, size_t ws_size,
                              hipStream_t stream)
{
    const float* x  = (const float*)d_in[0];
    const float* Wq = (const float*)d_in[1];
    const float* Wk = (const float*)d_in[2];
    const float* Wv = (const float*)d_in[3];
    const float* Wo = (const float*)d_in[4];
    const float* bo = (const float*)d_in[5];
    float* out = (float*)d_out;

    const size_t NEL = (size_t)BATCH * SEQ * DMODEL;
    const size_t WEL = (size_t)DMODEL * DMODEL;
    ushort_t* Qb  = (ushort_t*)d_ws;
    ushort_t* Kb  = Qb + NEL;
    ushort_t* Vb  = Kb + NEL;
    ushort_t* XAb = Vb + NEL;                          // x bf16, later attn out
    float*    Zb  = (float*)(XAb + NEL);
    ushort_t* WTq = (ushort_t*)(Zb + (size_t)BATCH * NH * SEQ);
    ushort_t* WTk = WTq + WEL;
    ushort_t* WTv = WTk + WEL;
    ushort_t* WTo = WTv + WEL;
    float*    Sl  = (float*)d_out;                     // scratch; final gemm overwrites

    const int M = BATCH * SEQ;
    dim3 gw(32, 32);
    dim3 gg(M / GBM, DMODEL / GBN);

    cvt_k<<<dim3(2048), dim3(256), 0, stream>>>(x, XAb, (int)(NEL / 4));
    wt_k<<<gw, dim3(256), 0, stream>>>(Wq, WTq);
    wt_k<<<gw, dim3(256), 0, stream>>>(Wk, WTk);
    wt_k<<<gw, dim3(256), 0, stream>>>(Wv, WTv);
    wt_k<<<gw, dim3(256), 0, stream>>>(Wo, WTo);

    mgemm_k<0><<<gg, dim3(256), 0, stream>>>(XAb, WTq, nullptr, Qb, M, DMODEL, DMODEL);
    mgemm_k<0><<<gg, dim3(256), 0, stream>>>(XAb, WTk, nullptr, Kb, M, DMODEL, DMODEL);
    mgemm_k<1><<<gg, dim3(256), 0, stream>>>(XAb, WTv, nullptr, Vb, M, DMODEL, DMODEL);

    z_k<<<dim3(BATCH * SEQ), dim3(64), 0, stream>>>(Qb, Kb, Zb);

    kv_k<<<dim3(BATCH * NH * NCHUNK), dim3(256), 0, stream>>>(Kb, Vb, Sl);
    scan_k<<<dim3(BATCH * NH, 16), dim3(256), 0, stream>>>(Sl);
    attn_k<<<dim3(BATCH * NH * NCHUNK), dim3(256), 0, stream>>>(Qb, Kb, Vb, Sl, Zb, XAb);

    mgemm_k<2><<<gg, dim3(256), 0, stream>>>(XAb, WTo, bo, out, M, DMODEL, DMODEL);
}

// Round 4
// 394.507 us; speedup vs baseline: 4.9584x; 1.1284x over previous
//
#include <hip/hip_runtime.h>
#include <hip/hip_bf16.h>

#define BATCH 4
#define SEQ   4096
#define DMODEL 1024
#define NH    16
#define DH    64
#define NCHUNK 32
#define CHUNKSZ 128
#define FEPS  1e-6f

typedef unsigned short ushort_t;
typedef __attribute__((ext_vector_type(8))) short short8;
typedef __attribute__((ext_vector_type(4))) float f32x4;

__device__ __forceinline__ float bf2f(ushort_t u) {
    union { unsigned int i; float f; } x; x.i = ((unsigned int)u) << 16; return x.f;
}
__device__ __forceinline__ ushort_t f2bf(float f) {
    union { float f; unsigned int i; } x; x.f = f;
    unsigned int lsb = (x.i >> 16) & 1u;
    x.i += 0x7fffu + lsb;   // round-to-nearest-even
    return (ushort_t)(x.i >> 16);
}

__device__ __forceinline__ void load_lds16(const void* g, void* l) {
    __builtin_amdgcn_global_load_lds(
        (const __attribute__((address_space(1))) int*)g,
        (__attribute__((address_space(3))) int*)l, 16, 0, 0);
}

// ---------------------------------------------------------------------------
// x f32 -> bf16 (same layout)
// ---------------------------------------------------------------------------
__global__ __launch_bounds__(256) void cvt_k(const float* __restrict__ X,
                                             ushort_t* __restrict__ Xb, int n4)
{
    int i = blockIdx.x * blockDim.x + threadIdx.x;
    int stride = gridDim.x * blockDim.x;
    for (; i < n4; i += stride) {
        float4 v = ((const float4*)X)[i];
        ushort4 u;
        u.x = f2bf(v.x); u.y = f2bf(v.y); u.z = f2bf(v.z); u.w = f2bf(v.w);
        ((ushort4*)Xb)[i] = u;
    }
}

// ---------------------------------------------------------------------------
// W f32 [K,N] -> WT bf16 [N,K]
// ---------------------------------------------------------------------------
__global__ __launch_bounds__(256) void wt_k(const float* __restrict__ W,
                                            ushort_t* __restrict__ WT)
{
    __shared__ float tile[32][33];
    int tx = threadIdx.x & 31, ty = threadIdx.x >> 5;
    int kb = blockIdx.x << 5, nb = blockIdx.y << 5;
#pragma unroll
    for (int i = 0; i < 4; i++)
        tile[ty + i * 8][tx] = W[(size_t)(kb + ty + i * 8) * DMODEL + nb + tx];
    __syncthreads();
#pragma unroll
    for (int i = 0; i < 4; i++)
        WT[(size_t)(nb + ty + i * 8) * DMODEL + kb + tx] = f2bf(tile[tx][ty + i * 8]);
}

// ---------------------------------------------------------------------------
// MFMA GEMM, 2-phase double-buffered pipeline (T3-minimum recipe).
// 128x128 tile, BK=32, 4 waves (2x2), 16x16x32 bf16 MFMA, global_load_lds w16.
// Loop body: STAGE(t+1 -> buf^1) ; ds_read(buf) ; MFMA ; __syncthreads().
// MODE 0: fused QKV. N=3072 over [WTq|WTk|WTv]; feature(elu+1) for n<2048;
//         bf16 scatter to Qb/Kb/Vb (contiguous, NEL apart) in [b,h,t,d].
// MODE 2: +bias, f32 row-major [M,N].
// ---------------------------------------------------------------------------
#define GBM 128
#define GBN 128
#define GBK 32

template<int MODE>
__global__ __launch_bounds__(256) void mgemm_k(const ushort_t* __restrict__ Ap,
                                               const ushort_t* __restrict__ Bt,
                                               const float* __restrict__ bias,
                                               void* __restrict__ Cp,
                                               int M, int N, int K)
{
    __shared__ short smem[16384];          // 2 x (As 4096 | Bs 4096) shorts
    const int tid = threadIdx.x;
    const int l  = tid & 63;
    const int w  = tid >> 6;
    const int wm = w >> 1, wn = w & 1;
    const int lr = l & 15;
    const int kc = l >> 4;

    const size_t m0 = (size_t)blockIdx.x * GBM;
    const size_t n0 = (size_t)blockIdx.y * GBN;

    f32x4 acc[4][4];
#pragma unroll
    for (int i = 0; i < 4; i++)
#pragma unroll
        for (int j = 0; j < 4; j++) acc[i][j] = (f32x4){0.f, 0.f, 0.f, 0.f};

    const int s0 = w * 2;
    auto STAGE = [&](short* dst, int k0) {
#pragma unroll
        for (int i = 0; i < 2; i++) {
            const int s   = s0 + i;
            const int kch = s >> 1;
            const int rh  = (s & 1) << 6;
            const int ldso = (kch * 128 + rh) * 8;
            load_lds16(Ap + (m0 + rh + l) * (size_t)K + k0 + kch * 8, dst + ldso);
            load_lds16(Bt + (n0 + rh + l) * (size_t)K + k0 + kch * 8, dst + 4096 + ldso);
        }
    };

    const int nt = K / GBK;
    STAGE(smem, 0);
    __syncthreads();                        // implicit vmcnt(0): tile 0 landed

    for (int t = 0; t < nt; ++t) {
        short* buf = smem + (t & 1) * 8192;
        short* nbuf = smem + ((t & 1) ^ 1) * 8192;
        if (t + 1 < nt) STAGE(nbuf, (t + 1) * GBK);   // flight hides under compute
        const short* As = buf;
        const short* Bs = buf + 4096;
        short8 af[4], bfr[4];
#pragma unroll
        for (int u = 0; u < 4; u++) {
            af[u]  = *(const short8*)(As + (kc * 128 + wm * 64 + u * 16 + lr) * 8);
            bfr[u] = *(const short8*)(Bs + (kc * 128 + wn * 64 + u * 16 + lr) * 8);
        }
#pragma unroll
        for (int mt = 0; mt < 4; mt++)
#pragma unroll
            for (int nt2 = 0; nt2 < 4; nt2++)
                acc[mt][nt2] = __builtin_amdgcn_mfma_f32_16x16x32_bf16(
                    af[mt], bfr[nt2], acc[mt][nt2], 0, 0, 0);
        __syncthreads();                    // single drain+barrier per K-step
    }

#pragma unroll
    for (int mt = 0; mt < 4; mt++) {
#pragma unroll
        for (int nt2 = 0; nt2 < 4; nt2++) {
#pragma unroll
            for (int j = 0; j < 4; j++) {
                int m = (int)m0 + wm * 64 + mt * 16 + (l >> 4) * 4 + j;
                int n = (int)n0 + wn * 64 + nt2 * 16 + lr;
                float v = acc[mt][nt2][j];
                if (MODE == 2) {
                    ((float*)Cp)[(size_t)m * N + n] = v + bias[n];
                } else {
                    if (n < 2048) v = (v > 0.f) ? (v + 1.f) : __expf(v);  // Q,K feature
                    int tns = n >> 10, nn = n & 1023;
                    int b_ = m >> 12, t_ = m & 4095, h_ = nn >> 6, d_ = nn & 63;
                    ushort_t* base = (ushort_t*)Cp + (size_t)tns * BATCH * SEQ * DMODEL;
                    base[((((size_t)b_ * NH + h_) * SEQ + t_) << 6) + d_] = f2bf(v);
                }
            }
        }
    }
}

// ---------------------------------------------------------------------------
// Z[b,h,t] = 1/(sum_d Q[b,h,t,d] * cumsum_{h'<=h} K[b,h',t,d] + eps)
// ---------------------------------------------------------------------------
__global__ __launch_bounds__(64) void z_k(const ushort_t* __restrict__ Q,
                                          const ushort_t* __restrict__ K,
                                          float* __restrict__ Z)
{
    int bt = blockIdx.x;
    int b_ = bt >> 12, t_ = bt & 4095;
    int d = threadIdx.x;
    float qv[NH], kv[NH];
    size_t base = (((size_t)b_ * NH) * SEQ + t_) * DH + d;
#pragma unroll
    for (int h = 0; h < NH; h++) {
        qv[h] = bf2f(Q[base + (size_t)h * SEQ * DH]);
        kv[h] = bf2f(K[base + (size_t)h * SEQ * DH]);
    }
    float ck = 0.f;
#pragma unroll
    for (int h = 0; h < NH; h++) {
        ck += kv[h];
        float p = qv[h] * ck;
#pragma unroll
        for (int off = 1; off < 64; off <<= 1) p += __shfl_xor(p, off, 64);
        if (d == 0) Z[((size_t)b_ * NH + h) * SEQ + t_] = 1.f / (p + FEPS);
    }
}

// ---------------------------------------------------------------------------
// Per-chunk S_local = K_c^T V_c  via MFMA
// ---------------------------------------------------------------------------
__global__ __launch_bounds__(256) void kv_k(const ushort_t* __restrict__ Kf,
                                            const ushort_t* __restrict__ Vf,
                                            float* __restrict__ Sloc)
{
    __shared__ short KTs[8192];
    __shared__ short VTs[8192];
    const int tid = threadIdx.x;
    const int l = tid & 63, w = tid >> 6;
    const int lr = l & 15, hi = l >> 4;
    const int blk = blockIdx.x;
    const size_t rowbase = ((size_t)(blk >> 5) * SEQ + (size_t)(blk & 31) * CHUNKSZ) * DH;
    const uint4* K16 = (const uint4*)(Kf + rowbase);
    const uint4* V16 = (const uint4*)(Vf + rowbase);
#pragma unroll
    for (int i = 0; i < 4; i++) {
        int idx = tid + i * 256;
        union { uint4 q; ushort_t us[8]; } kk, vv;
        kk.q = K16[idx]; vv.q = V16[idx];
        int j = idx >> 3, e0 = (idx & 7) << 3;
#pragma unroll
        for (int s = 0; s < 8; s++) {
            int off = ((j >> 3) * 64 + e0 + s) * 8 + (j & 7);
            KTs[off] = (short)kk.us[s];
            VTs[off] = (short)vv.us[s];
        }
    }
    __syncthreads();
    f32x4 acc[4];
#pragma unroll
    for (int nt = 0; nt < 4; nt++) acc[nt] = (f32x4){0.f, 0.f, 0.f, 0.f};
#pragma unroll
    for (int ks = 0; ks < 4; ks++) {
        short8 af = *(const short8*)(KTs + ((ks * 4 + hi) * 64 + w * 16 + lr) * 8);
        short8 bf[4];
#pragma unroll
        for (int nt = 0; nt < 4; nt++)
            bf[nt] = *(const short8*)(VTs + ((ks * 4 + hi) * 64 + nt * 16 + lr) * 8);
#pragma unroll
        for (int nt = 0; nt < 4; nt++)
            acc[nt] = __builtin_amdgcn_mfma_f32_16x16x32_bf16(af, bf[nt], acc[nt], 0, 0, 0);
    }
    float* outp = Sloc + (size_t)blk * DH * DH;
#pragma unroll
    for (int nt = 0; nt < 4; nt++)
#pragma unroll
        for (int jr = 0; jr < 4; jr++) {
            int d_ = w * 16 + hi * 4 + jr;
            int e_ = nt * 16 + lr;
            outp[d_ * DH + e_] = acc[nt][jr];
        }
}

// ---------------------------------------------------------------------------
// Exclusive prefix over chunks, element-parallel
// ---------------------------------------------------------------------------
__global__ __launch_bounds__(256) void scan_k(float* __restrict__ Sloc)
{
    int bh = blockIdx.x, seg = blockIdx.y;
    int e = seg * 256 + threadIdx.x;
    float* base = Sloc + (size_t)bh * NCHUNK * DH * DH + e;
    float acc = 0.f;
    float cur = base[0];
    for (int cc = 0; cc < NCHUNK; cc++) {
        float nxt = (cc + 1 < NCHUNK) ? base[(size_t)(cc + 1) * DH * DH] : 0.f;
        base[(size_t)cc * DH * DH] = acc;
        acc += cur;
        cur = nxt;
    }
}

// ---------------------------------------------------------------------------
// MFMA attention chunk kernel (validated round 3)
// ---------------------------------------------------------------------------
__global__ __launch_bounds__(256) void attn_k(const ushort_t* __restrict__ Qf,
                                              const ushort_t* __restrict__ Kf,
                                              const ushort_t* __restrict__ Vf,
                                              const float* __restrict__ Sloc,
                                              const float* __restrict__ Z,
                                              ushort_t* __restrict__ A)
{
    __shared__ short smem[36864];
    short* Qs  = smem;
    short* Ks  = smem + 8192;
    short* Ps  = smem + 8192;
    short* VTs = smem + 24576;
    short* STs = smem + 32768;

    const int tid = threadIdx.x;
    const int l = tid & 63, w = tid >> 6;
    const int lr = l & 15, hi = l >> 4;
    const int blk = blockIdx.x;
    const int c = blk & (NCHUNK - 1), bh = blk >> 5;
    const int b_ = bh >> 4, h_ = bh & 15;
    const size_t rowbase = ((size_t)bh * SEQ + (size_t)c * CHUNKSZ) * DH;

#pragma unroll
    for (int ii = 0; ii < 4; ii++) {
        int s = w * 4 + ii;
        int kc = s >> 1, rh = (s & 1) << 6;
        int ldso = (kc * 128 + rh) * 8;
        load_lds16(Qf + rowbase + (size_t)(rh + l) * DH + kc * 8, Qs + ldso);
        load_lds16(Kf + rowbase + (size_t)(rh + l) * DH + kc * 8, Ks + ldso);
    }
    {
        const uint4* V16 = (const uint4*)(Vf + rowbase);
#pragma unroll
        for (int i = 0; i < 4; i++) {
            int idx = tid + i * 256;
            union { uint4 q; ushort_t us[8]; } vv;
            vv.q = V16[idx];
            int j = idx >> 3, e0 = (idx & 7) << 3;
#pragma unroll
            for (int s = 0; s < 8; s++)
                VTs[((j >> 3) * 64 + e0 + s) * 8 + (j & 7)] = (short)vv.us[s];
        }
    }
    {
        const float4* S16 = (const float4*)(Sloc + (size_t)blk * DH * DH);
#pragma unroll
        for (int i = 0; i < 4; i++) {
            int idx = tid + i * 256;
            float4 f = S16[idx];
            int d = idx >> 4, e0 = (idx & 15) << 2;
            STs[((d >> 3) * 64 + e0 + 0) * 8 + (d & 7)] = (short)f2bf(f.x);
            STs[((d >> 3) * 64 + e0 + 1) * 8 + (d & 7)] = (short)f2bf(f.y);
            STs[((d >> 3) * 64 + e0 + 2) * 8 + (d & 7)] = (short)f2bf(f.z);
            STs[((d >> 3) * 64 + e0 + 3) * 8 + (d & 7)] = (short)f2bf(f.w);
        }
    }
    __syncthreads();

    f32x4 acc1[2][8];
#pragma unroll
    for (int mt = 0; mt < 2; mt++)
#pragma unroll
        for (int nt = 0; nt < 8; nt++) acc1[mt][nt] = (f32x4){0.f, 0.f, 0.f, 0.f};
#pragma unroll
    for (int ks = 0; ks < 2; ks++) {
        short8 af[2], bf[8];
#pragma unroll
        for (int mt = 0; mt < 2; mt++)
            af[mt] = *(const short8*)(Qs + ((ks * 4 + hi) * 128 + w * 32 + mt * 16 + lr) * 8);
#pragma unroll
        for (int nt = 0; nt < 8; nt++)
            bf[nt] = *(const short8*)(Ks + ((ks * 4 + hi) * 128 + nt * 16 + lr) * 8);
#pragma unroll
        for (int mt = 0; mt < 2; mt++)
#pragma unroll
            for (int nt = 0; nt < 8; nt++)
                acc1[mt][nt] = __builtin_amdgcn_mfma_f32_16x16x32_bf16(
                    af[mt], bf[nt], acc1[mt][nt], 0, 0, 0);
    }
    __syncthreads();

#pragma unroll
    for (int mt = 0; mt < 2; mt++)
#pragma unroll
        for (int nt = 0; nt < 8; nt++)
#pragma unroll
            for (int jr = 0; jr < 4; jr++) {
                int i_ = w * 32 + mt * 16 + hi * 4 + jr;
                int j_ = nt * 16 + lr;
                float v = (j_ <= i_) ? acc1[mt][nt][jr] : 0.f;
                Ps[((j_ >> 3) * 128 + i_) * 8 + (j_ & 7)] = (short)f2bf(v);
            }
    __syncthreads();

    f32x4 acc2[2][4];
#pragma unroll
    for (int mt = 0; mt < 2; mt++)
#pragma unroll
        for (int nt = 0; nt < 4; nt++) acc2[mt][nt] = (f32x4){0.f, 0.f, 0.f, 0.f};
#pragma unroll
    for (int ks = 0; ks < 4; ks++) {
        short8 af[2], bf[4];
#pragma unroll
        for (int mt = 0; mt < 2; mt++)
            af[mt] = *(const short8*)(Ps + ((ks * 4 + hi) * 128 + w * 32 + mt * 16 + lr) * 8);
#pragma unroll
        for (int nt = 0; nt < 4; nt++)
            bf[nt] = *(const short8*)(VTs + ((ks * 4 + hi) * 64 + nt * 16 + lr) * 8);
#pragma unroll
        for (int mt = 0; mt < 2; mt++)
#pragma unroll
            for (int nt = 0; nt < 4; nt++)
                acc2[mt][nt] = __builtin_amdgcn_mfma_f32_16x16x32_bf16(
                    af[mt], bf[nt], acc2[mt][nt], 0, 0, 0);
    }
#pragma unroll
    for (int ks = 0; ks < 2; ks++) {
        short8 af[2], bf[4];
#pragma unroll
        for (int mt = 0; mt < 2; mt++)
            af[mt] = *(const short8*)(Qs + ((ks * 4 + hi) * 128 + w * 32 + mt * 16 + lr) * 8);
#pragma unroll
        for (int nt = 0; nt < 4; nt++)
            bf[nt] = *(const short8*)(STs + ((ks * 4 + hi) * 64 + nt * 16 + lr) * 8);
#pragma unroll
        for (int mt = 0; mt < 2; mt++)
#pragma unroll
            for (int nt = 0; nt < 4; nt++)
                acc2[mt][nt] = __builtin_amdgcn_mfma_f32_16x16x32_bf16(
                    af[mt], bf[nt], acc2[mt][nt], 0, 0, 0);
    }

#pragma unroll
    for (int mt = 0; mt < 2; mt++) {
#pragma unroll
        for (int jr = 0; jr < 4; jr++) {
            int i_ = w * 32 + mt * 16 + hi * 4 + jr;
            int t_ = c * CHUNKSZ + i_;
            float z = Z[(size_t)bh * SEQ + t_];
            ushort_t* op = A + (((size_t)(b_ * SEQ + t_)) * NH + h_) * DH;
#pragma unroll
            for (int nt = 0; nt < 4; nt++)
                op[nt * 16 + lr] = f2bf(acc2[mt][nt][jr] * z);
        }
    }
}

// ---------------------------------------------------------------------------
extern "C" void kernel_launch(void* const* d_in, const int* in_sizes, int n_in,
                              void* d_out, int out_size, void* d_ws, size_t ws_size,
                              hipStream_t stream)
{
    const float* x  = (const float*)d_in[0];
    const float* Wq = (const float*)d_in[1];
    const float* Wk = (const float*)d_in[2];
    const float* Wv = (const float*)d_in[3];
    const float* Wo = (const float*)d_in[4];
    const float* bo = (const float*)d_in[5];
    float* out = (float*)d_out;

    const size_t NEL = (size_t)BATCH * SEQ * DMODEL;
    const size_t WEL = (size_t)DMODEL * DMODEL;
    ushort_t* Qb  = (ushort_t*)d_ws;                   // Q,K,V contiguous (fused scatter)
    ushort_t* Kb  = Qb + NEL;
    ushort_t* Vb  = Kb + NEL;
    ushort_t* XAb = Vb + NEL;                          // x bf16, later attn out
    float*    Zb  = (float*)(XAb + NEL);
    ushort_t* WTq = (ushort_t*)(Zb + (size_t)BATCH * NH * SEQ);  // WTq|WTk|WTv contiguous
    ushort_t* WTk = WTq + WEL;
    ushort_t* WTv = WTk + WEL;
    ushort_t* WTo = WTv + WEL;
    float*    Sl  = (float*)d_out;                     // scratch; final gemm overwrites

    const int M = BATCH * SEQ;
    dim3 gw(32, 32);

    cvt_k<<<dim3(2048), dim3(256), 0, stream>>>(x, XAb, (int)(NEL / 4));
    wt_k<<<gw, dim3(256), 0, stream>>>(Wq, WTq);
    wt_k<<<gw, dim3(256), 0, stream>>>(Wk, WTk);
    wt_k<<<gw, dim3(256), 0, stream>>>(Wv, WTv);
    wt_k<<<gw, dim3(256), 0, stream>>>(Wo, WTo);

    // fused QKV: N = 3072 over concatenated [WTq|WTk|WTv]
    mgemm_k<0><<<dim3(M / GBM, 3 * DMODEL / GBN), dim3(256), 0, stream>>>(
        XAb, WTq, nullptr, Qb, M, 3 * DMODEL, DMODEL);

    z_k<<<dim3(BATCH * SEQ), dim3(64), 0, stream>>>(Qb, Kb, Zb);

    kv_k<<<dim3(BATCH * NH * NCHUNK), dim3(256), 0, stream>>>(Kb, Vb, Sl);
    scan_k<<<dim3(BATCH * NH, 16), dim3(256), 0, stream>>>(Sl);
    attn_k<<<dim3(BATCH * NH * NCHUNK), dim3(256), 0, stream>>>(Qb, Kb, Vb, Sl, Zb, XAb);

    mgemm_k<2><<<dim3(M / GBM, DMODEL / GBN), dim3(256), 0, stream>>>(
        XAb, WTo, bo, out, M, DMODEL, DMODEL);
}

// Round 5
// 310.956 us; speedup vs baseline: 6.2907x; 1.2687x over previous
//
#include <hip/hip_runtime.h>
#include <hip/hip_bf16.h>

#define BATCH 4
#define SEQ   4096
#define DMODEL 1024
#define NH    16
#define DH    64
#define NCHUNK 32
#define CHUNKSZ 128
#define FEPS  1e-6f

typedef unsigned short ushort_t;
typedef __attribute__((ext_vector_type(8))) short short8;
typedef __attribute__((ext_vector_type(4))) float f32x4;

__device__ __forceinline__ float bf2f(ushort_t u) {
    union { unsigned int i; float f; } x; x.i = ((unsigned int)u) << 16; return x.f;
}
__device__ __forceinline__ ushort_t f2bf(float f) {
    union { float f; unsigned int i; } x; x.f = f;
    unsigned int lsb = (x.i >> 16) & 1u;
    x.i += 0x7fffu + lsb;   // round-to-nearest-even
    return (ushort_t)(x.i >> 16);
}

__device__ __forceinline__ void load_lds16(const void* g, void* l) {
    __builtin_amdgcn_global_load_lds(
        (const __attribute__((address_space(1))) int*)g,
        (__attribute__((address_space(3))) int*)l, 16, 0, 0);
}

// ---------------------------------------------------------------------------
// x f32 -> bf16 (same layout)
// ---------------------------------------------------------------------------
__global__ __launch_bounds__(256) void cvt_k(const float* __restrict__ X,
                                             ushort_t* __restrict__ Xb, int n4)
{
    int i = blockIdx.x * blockDim.x + threadIdx.x;
    int stride = gridDim.x * blockDim.x;
    for (; i < n4; i += stride) {
        float4 v = ((const float4*)X)[i];
        ushort4 u;
        u.x = f2bf(v.x); u.y = f2bf(v.y); u.z = f2bf(v.z); u.w = f2bf(v.w);
        ((ushort4*)Xb)[i] = u;
    }
}

// ---------------------------------------------------------------------------
// W f32 [K,N] -> WT bf16 [N,K]
// ---------------------------------------------------------------------------
__global__ __launch_bounds__(256) void wt_k(const float* __restrict__ W,
                                            ushort_t* __restrict__ WT)
{
    __shared__ float tile[32][33];
    int tx = threadIdx.x & 31, ty = threadIdx.x >> 5;
    int kb = blockIdx.x << 5, nb = blockIdx.y << 5;
#pragma unroll
    for (int i = 0; i < 4; i++)
        tile[ty + i * 8][tx] = W[(size_t)(kb + ty + i * 8) * DMODEL + nb + tx];
    __syncthreads();
#pragma unroll
    for (int i = 0; i < 4; i++)
        WT[(size_t)(nb + ty + i * 8) * DMODEL + kb + tx] = f2bf(tile[tx][ty + i * 8]);
}

// ---------------------------------------------------------------------------
// MFMA GEMM, 3-slot ring + counted vmcnt (T3+T4 at K-tile granularity).
// 256x256 tile, BK=32, 8 waves (2M x 4N), 16x16x32 bf16 MFMA.
// LDS: 3 slots x (A[4][256][8] | B[4][256][8]) = 96 KB, conflict-free reads.
// Loop t: STAGE(t+2 -> slot[(t+2)%3]) ; ds_read+MFMA slot[t%3] ;
//         s_waitcnt vmcnt(4) (t+1 landed, t+2 in flight) ; lgkmcnt(0) ;
//         sched_barrier ; s_barrier.   Never drains vmcnt to 0 mid-loop.
// MODE 0: fused QKV. N=3072 over [WTq|WTk|WTv]; feature(elu+1) for n<2048;
//         bf16 scatter to Qb/Kb/Vb in [b,h,t,d].
// MODE 2: +bias, f32 row-major [M,N].
// ---------------------------------------------------------------------------
#define TBM 256
#define TBN 256
#define TBK 32

template<int MODE>
__global__ __launch_bounds__(512, 2) void mgemm3_k(const ushort_t* __restrict__ Ap,
                                                   const ushort_t* __restrict__ Bt,
                                                   const float* __restrict__ bias,
                                                   void* __restrict__ Cp,
                                                   int M, int N, int K)
{
    __shared__ short smem[49152];              // 3 x (A 8192 | B 8192) shorts
    const int tid = threadIdx.x;
    const int l  = tid & 63;
    const int w  = tid >> 6;
    const int wm = w >> 2, wn = w & 3;         // 2 x 4 wave grid
    const int lr = l & 15;
    const int kc = l >> 4;

    const size_t m0 = (size_t)blockIdx.x * TBM;
    const size_t n0 = (size_t)blockIdx.y * TBN;

    f32x4 acc[8][4];
#pragma unroll
    for (int i = 0; i < 8; i++)
#pragma unroll
        for (int j = 0; j < 4; j++) acc[i][j] = (f32x4){0.f, 0.f, 0.f, 0.f};

    auto STAGE = [&](int slot, int k0) {
        short* Asl = smem + slot * 16384;
        short* Bsl = Asl + 8192;
#pragma unroll
        for (int i = 0; i < 2; i++) {
            const int sa  = w * 2 + i;          // 0..15 segments of 1KB
            const int kch = sa >> 2;            // k-chunk 0..3
            const int rb  = sa & 3;             // row-block of 64
            const int ldso = (kch * 256 + rb * 64) * 8;
            load_lds16(Ap + (m0 + rb * 64 + l) * (size_t)K + k0 + kch * 8, Asl + ldso);
            load_lds16(Bt + (n0 + rb * 64 + l) * (size_t)K + k0 + kch * 8, Bsl + ldso);
        }
    };

    const int nt = K / TBK;                     // 32 for K=1024
    STAGE(0, 0);
    STAGE(1, TBK);
    asm volatile("s_waitcnt vmcnt(4)" ::: "memory");   // slot0 landed; slot1 in flight
    __builtin_amdgcn_sched_barrier(0);
    __builtin_amdgcn_s_barrier();

    for (int t = 0; t < nt; ++t) {
        if (t + 2 < nt) STAGE((t + 2) % 3, (t + 2) * TBK);
        const short* Asl = smem + (t % 3) * 16384;
        const short* Bsl = Asl + 8192;
        short8 af[8], bf[4];
#pragma unroll
        for (int mt = 0; mt < 8; mt++)
            af[mt] = *(const short8*)(Asl + (kc * 256 + wm * 128 + mt * 16 + lr) * 8);
#pragma unroll
        for (int nn = 0; nn < 4; nn++)
            bf[nn] = *(const short8*)(Bsl + (kc * 256 + wn * 64 + nn * 16 + lr) * 8);
#pragma unroll
        for (int mt = 0; mt < 8; mt++)
#pragma unroll
            for (int nn = 0; nn < 4; nn++)
                acc[mt][nn] = __builtin_amdgcn_mfma_f32_16x16x32_bf16(
                    af[mt], bf[nn], acc[mt][nn], 0, 0, 0);
        if (t + 2 < nt) {
            asm volatile("s_waitcnt vmcnt(4)" ::: "memory");   // t+1 landed
        } else {
            asm volatile("s_waitcnt vmcnt(0)" ::: "memory");   // tail drain
        }
        asm volatile("s_waitcnt lgkmcnt(0)" ::: "memory");     // my ds_reads done
        __builtin_amdgcn_sched_barrier(0);
        __builtin_amdgcn_s_barrier();
    }

    // epilogue: row = m0 + wm*128 + mt*16 + (l>>4)*4 + j ; col = n0 + wn*64 + nn*16 + lr
#pragma unroll
    for (int mt = 0; mt < 8; mt++) {
#pragma unroll
        for (int nn = 0; nn < 4; nn++) {
#pragma unroll
            for (int j = 0; j < 4; j++) {
                int m = (int)m0 + wm * 128 + mt * 16 + (l >> 4) * 4 + j;
                int n = (int)n0 + wn * 64 + nn * 16 + lr;
                float v = acc[mt][nn][j];
                if (MODE == 2) {
                    ((float*)Cp)[(size_t)m * N + n] = v + bias[n];
                } else {
                    if (n < 2048) v = (v > 0.f) ? (v + 1.f) : __expf(v);  // Q,K feature
                    int tns = n >> 10, nnn = n & 1023;
                    int b_ = m >> 12, t_ = m & 4095, h_ = nnn >> 6, d_ = nnn & 63;
                    ushort_t* base = (ushort_t*)Cp + (size_t)tns * BATCH * SEQ * DMODEL;
                    base[((((size_t)b_ * NH + h_) * SEQ + t_) << 6) + d_] = f2bf(v);
                }
            }
        }
    }
}

// ---------------------------------------------------------------------------
// Z[b,h,t] = 1/(sum_d Q[b,h,t,d] * cumsum_{h'<=h} K[b,h',t,d] + eps)
// ---------------------------------------------------------------------------
__global__ __launch_bounds__(64) void z_k(const ushort_t* __restrict__ Q,
                                          const ushort_t* __restrict__ K,
                                          float* __restrict__ Z)
{
    int bt = blockIdx.x;
    int b_ = bt >> 12, t_ = bt & 4095;
    int d = threadIdx.x;
    float qv[NH], kv[NH];
    size_t base = (((size_t)b_ * NH) * SEQ + t_) * DH + d;
#pragma unroll
    for (int h = 0; h < NH; h++) {
        qv[h] = bf2f(Q[base + (size_t)h * SEQ * DH]);
        kv[h] = bf2f(K[base + (size_t)h * SEQ * DH]);
    }
    float ck = 0.f;
#pragma unroll
    for (int h = 0; h < NH; h++) {
        ck += kv[h];
        float p = qv[h] * ck;
#pragma unroll
        for (int off = 1; off < 64; off <<= 1) p += __shfl_xor(p, off, 64);
        if (d == 0) Z[((size_t)b_ * NH + h) * SEQ + t_] = 1.f / (p + FEPS);
    }
}

// ---------------------------------------------------------------------------
// Per-chunk S_local = K_c^T V_c  via MFMA
// ---------------------------------------------------------------------------
__global__ __launch_bounds__(256) void kv_k(const ushort_t* __restrict__ Kf,
                                            const ushort_t* __restrict__ Vf,
                                            float* __restrict__ Sloc)
{
    __shared__ short KTs[8192];
    __shared__ short VTs[8192];
    const int tid = threadIdx.x;
    const int l = tid & 63, w = tid >> 6;
    const int lr = l & 15, hi = l >> 4;
    const int blk = blockIdx.x;
    const size_t rowbase = ((size_t)(blk >> 5) * SEQ + (size_t)(blk & 31) * CHUNKSZ) * DH;
    const uint4* K16 = (const uint4*)(Kf + rowbase);
    const uint4* V16 = (const uint4*)(Vf + rowbase);
#pragma unroll
    for (int i = 0; i < 4; i++) {
        int idx = tid + i * 256;
        union { uint4 q; ushort_t us[8]; } kk, vv;
        kk.q = K16[idx]; vv.q = V16[idx];
        int j = idx >> 3, e0 = (idx & 7) << 3;
#pragma unroll
        for (int s = 0; s < 8; s++) {
            int off = ((j >> 3) * 64 + e0 + s) * 8 + (j & 7);
            KTs[off] = (short)kk.us[s];
            VTs[off] = (short)vv.us[s];
        }
    }
    __syncthreads();
    f32x4 acc[4];
#pragma unroll
    for (int nt = 0; nt < 4; nt++) acc[nt] = (f32x4){0.f, 0.f, 0.f, 0.f};
#pragma unroll
    for (int ks = 0; ks < 4; ks++) {
        short8 af = *(const short8*)(KTs + ((ks * 4 + hi) * 64 + w * 16 + lr) * 8);
        short8 bf[4];
#pragma unroll
        for (int nt = 0; nt < 4; nt++)
            bf[nt] = *(const short8*)(VTs + ((ks * 4 + hi) * 64 + nt * 16 + lr) * 8);
#pragma unroll
        for (int nt = 0; nt < 4; nt++)
            acc[nt] = __builtin_amdgcn_mfma_f32_16x16x32_bf16(af, bf[nt], acc[nt], 0, 0, 0);
    }
    float* outp = Sloc + (size_t)blk * DH * DH;
#pragma unroll
    for (int nt = 0; nt < 4; nt++)
#pragma unroll
        for (int jr = 0; jr < 4; jr++) {
            int d_ = w * 16 + hi * 4 + jr;
            int e_ = nt * 16 + lr;
            outp[d_ * DH + e_] = acc[nt][jr];
        }
}

// ---------------------------------------------------------------------------
// Exclusive prefix over chunks, element-parallel
// ---------------------------------------------------------------------------
__global__ __launch_bounds__(256) void scan_k(float* __restrict__ Sloc)
{
    int bh = blockIdx.x, seg = blockIdx.y;
    int e = seg * 256 + threadIdx.x;
    float* base = Sloc + (size_t)bh * NCHUNK * DH * DH + e;
    float acc = 0.f;
    float cur = base[0];
    for (int cc = 0; cc < NCHUNK; cc++) {
        float nxt = (cc + 1 < NCHUNK) ? base[(size_t)(cc + 1) * DH * DH] : 0.f;
        base[(size_t)cc * DH * DH] = acc;
        acc += cur;
        cur = nxt;
    }
}

// ---------------------------------------------------------------------------
// MFMA attention chunk kernel (validated round 3)
// ---------------------------------------------------------------------------
__global__ __launch_bounds__(256) void attn_k(const ushort_t* __restrict__ Qf,
                                              const ushort_t* __restrict__ Kf,
                                              const ushort_t* __restrict__ Vf,
                                              const float* __restrict__ Sloc,
                                              const float* __restrict__ Z,
                                              ushort_t* __restrict__ A)
{
    __shared__ short smem[36864];
    short* Qs  = smem;
    short* Ks  = smem + 8192;
    short* Ps  = smem + 8192;
    short* VTs = smem + 24576;
    short* STs = smem + 32768;

    const int tid = threadIdx.x;
    const int l = tid & 63, w = tid >> 6;
    const int lr = l & 15, hi = l >> 4;
    const int blk = blockIdx.x;
    const int c = blk & (NCHUNK - 1), bh = blk >> 5;
    const int b_ = bh >> 4, h_ = bh & 15;
    const size_t rowbase = ((size_t)bh * SEQ + (size_t)c * CHUNKSZ) * DH;

#pragma unroll
    for (int ii = 0; ii < 4; ii++) {
        int s = w * 4 + ii;
        int kc2 = s >> 1, rh = (s & 1) << 6;
        int ldso = (kc2 * 128 + rh) * 8;
        load_lds16(Qf + rowbase + (size_t)(rh + l) * DH + kc2 * 8, Qs + ldso);
        load_lds16(Kf + rowbase + (size_t)(rh + l) * DH + kc2 * 8, Ks + ldso);
    }
    {
        const uint4* V16 = (const uint4*)(Vf + rowbase);
#pragma unroll
        for (int i = 0; i < 4; i++) {
            int idx = tid + i * 256;
            union { uint4 q; ushort_t us[8]; } vv;
            vv.q = V16[idx];
            int j = idx >> 3, e0 = (idx & 7) << 3;
#pragma unroll
            for (int s = 0; s < 8; s++)
                VTs[((j >> 3) * 64 + e0 + s) * 8 + (j & 7)] = (short)vv.us[s];
        }
    }
    {
        const float4* S16 = (const float4*)(Sloc + (size_t)blk * DH * DH);
#pragma unroll
        for (int i = 0; i < 4; i++) {
            int idx = tid + i * 256;
            float4 f = S16[idx];
            int d = idx >> 4, e0 = (idx & 15) << 2;
            STs[((d >> 3) * 64 + e0 + 0) * 8 + (d & 7)] = (short)f2bf(f.x);
            STs[((d >> 3) * 64 + e0 + 1) * 8 + (d & 7)] = (short)f2bf(f.y);
            STs[((d >> 3) * 64 + e0 + 2) * 8 + (d & 7)] = (short)f2bf(f.z);
            STs[((d >> 3) * 64 + e0 + 3) * 8 + (d & 7)] = (short)f2bf(f.w);
        }
    }
    __syncthreads();

    f32x4 acc1[2][8];
#pragma unroll
    for (int mt = 0; mt < 2; mt++)
#pragma unroll
        for (int nt = 0; nt < 8; nt++) acc1[mt][nt] = (f32x4){0.f, 0.f, 0.f, 0.f};
#pragma unroll
    for (int ks = 0; ks < 2; ks++) {
        short8 af[2], bf[8];
#pragma unroll
        for (int mt = 0; mt < 2; mt++)
            af[mt] = *(const short8*)(Qs + ((ks * 4 + hi) * 128 + w * 32 + mt * 16 + lr) * 8);
#pragma unroll
        for (int nt = 0; nt < 8; nt++)
            bf[nt] = *(const short8*)(Ks + ((ks * 4 + hi) * 128 + nt * 16 + lr) * 8);
#pragma unroll
        for (int mt = 0; mt < 2; mt++)
#pragma unroll
            for (int nt = 0; nt < 8; nt++)
                acc1[mt][nt] = __builtin_amdgcn_mfma_f32_16x16x32_bf16(
                    af[mt], bf[nt], acc1[mt][nt], 0, 0, 0);
    }
    __syncthreads();

#pragma unroll
    for (int mt = 0; mt < 2; mt++)
#pragma unroll
        for (int nt = 0; nt < 8; nt++)
#pragma unroll
            for (int jr = 0; jr < 4; jr++) {
                int i_ = w * 32 + mt * 16 + hi * 4 + jr;
                int j_ = nt * 16 + lr;
                float v = (j_ <= i_) ? acc1[mt][nt][jr] : 0.f;
                Ps[((j_ >> 3) * 128 + i_) * 8 + (j_ & 7)] = (short)f2bf(v);
            }
    __syncthreads();

    f32x4 acc2[2][4];
#pragma unroll
    for (int mt = 0; mt < 2; mt++)
#pragma unroll
        for (int nt = 0; nt < 4; nt++) acc2[mt][nt] = (f32x4){0.f, 0.f, 0.f, 0.f};
#pragma unroll
    for (int ks = 0; ks < 4; ks++) {
        short8 af[2], bf[4];
#pragma unroll
        for (int mt = 0; mt < 2; mt++)
            af[mt] = *(const short8*)(Ps + ((ks * 4 + hi) * 128 + w * 32 + mt * 16 + lr) * 8);
#pragma unroll
        for (int nt = 0; nt < 4; nt++)
            bf[nt] = *(const short8*)(VTs + ((ks * 4 + hi) * 64 + nt * 16 + lr) * 8);
#pragma unroll
        for (int mt = 0; mt < 2; mt++)
#pragma unroll
            for (int nt = 0; nt < 4; nt++)
                acc2[mt][nt] = __builtin_amdgcn_mfma_f32_16x16x32_bf16(
                    af[mt], bf[nt], acc2[mt][nt], 0, 0, 0);
    }
#pragma unroll
    for (int ks = 0; ks < 2; ks++) {
        short8 af[2], bf[4];
#pragma unroll
        for (int mt = 0; mt < 2; mt++)
            af[mt] = *(const short8*)(Qs + ((ks * 4 + hi) * 128 + w * 32 + mt * 16 + lr) * 8);
#pragma unroll
        for (int nt = 0; nt < 4; nt++)
            bf[nt] = *(const short8*)(STs + ((ks * 4 + hi) * 64 + nt * 16 + lr) * 8);
#pragma unroll
        for (int mt = 0; mt < 2; mt++)
#pragma unroll
            for (int nt = 0; nt < 4; nt++)
                acc2[mt][nt] = __builtin_amdgcn_mfma_f32_16x16x32_bf16(
                    af[mt], bf[nt], acc2[mt][nt], 0, 0, 0);
    }

#pragma unroll
    for (int mt = 0; mt < 2; mt++) {
#pragma unroll
        for (int jr = 0; jr < 4; jr++) {
            int i_ = w * 32 + mt * 16 + hi * 4 + jr;
            int t_ = c * CHUNKSZ + i_;
            float z = Z[(size_t)bh * SEQ + t_];
            ushort_t* op = A + (((size_t)(b_ * SEQ + t_)) * NH + h_) * DH;
#pragma unroll
            for (int nt = 0; nt < 4; nt++)
                op[nt * 16 + lr] = f2bf(acc2[mt][nt][jr] * z);
        }
    }
}

// ---------------------------------------------------------------------------
extern "C" void kernel_launch(void* const* d_in, const int* in_sizes, int n_in,
                              void* d_out, int out_size, void* d_ws, size_t ws_size,
                              hipStream_t stream)
{
    const float* x  = (const float*)d_in[0];
    const float* Wq = (const float*)d_in[1];
    const float* Wk = (const float*)d_in[2];
    const float* Wv = (const float*)d_in[3];
    const float* Wo = (const float*)d_in[4];
    const float* bo = (const float*)d_in[5];
    float* out = (float*)d_out;

    const size_t NEL = (size_t)BATCH * SEQ * DMODEL;
    const size_t WEL = (size_t)DMODEL * DMODEL;
    ushort_t* Qb  = (ushort_t*)d_ws;                   // Q,K,V contiguous (fused scatter)
    ushort_t* Kb  = Qb + NEL;
    ushort_t* Vb  = Kb + NEL;
    ushort_t* XAb = Vb + NEL;                          // x bf16, later attn out
    float*    Zb  = (float*)(XAb + NEL);
    ushort_t* WTq = (ushort_t*)(Zb + (size_t)BATCH * NH * SEQ);  // WTq|WTk|WTv contiguous
    ushort_t* WTk = WTq + WEL;
    ushort_t* WTv = WTk + WEL;
    ushort_t* WTo = WTv + WEL;
    float*    Sl  = (float*)d_out;                     // scratch; final gemm overwrites

    const int M = BATCH * SEQ;
    dim3 gw(32, 32);

    cvt_k<<<dim3(2048), dim3(256), 0, stream>>>(x, XAb, (int)(NEL / 4));
    wt_k<<<gw, dim3(256), 0, stream>>>(Wq, WTq);
    wt_k<<<gw, dim3(256), 0, stream>>>(Wk, WTk);
    wt_k<<<gw, dim3(256), 0, stream>>>(Wv, WTv);
    wt_k<<<gw, dim3(256), 0, stream>>>(Wo, WTo);

    // fused QKV: N = 3072 over concatenated [WTq|WTk|WTv]
    mgemm3_k<0><<<dim3(M / TBM, 3 * DMODEL / TBN), dim3(512), 0, stream>>>(
        XAb, WTq, nullptr, Qb, M, 3 * DMODEL, DMODEL);

    z_k<<<dim3(BATCH * SEQ), dim3(64), 0, stream>>>(Qb, Kb, Zb);

    kv_k<<<dim3(BATCH * NH * NCHUNK), dim3(256), 0, stream>>>(Kb, Vb, Sl);
    scan_k<<<dim3(BATCH * NH, 16), dim3(256), 0, stream>>>(Sl);
    attn_k<<<dim3(BATCH * NH * NCHUNK), dim3(256), 0, stream>>>(Qb, Kb, Vb, Sl, Zb, XAb);

    mgemm3_k<2><<<dim3(M / TBM, DMODEL / TBN), dim3(512), 0, stream>>>(
        XAb, WTo, bo, out, M, DMODEL, DMODEL);
}

// Round 6
// 304.943 us; speedup vs baseline: 6.4148x; 1.0197x over previous
//
#include <hip/hip_runtime.h>
#include <hip/hip_bf16.h>

#define BATCH 4
#define SEQ   4096
#define DMODEL 1024
#define NH    16
#define DH    64
#define NCHUNK 32
#define CHUNKSZ 128
#define FEPS  1e-6f

typedef unsigned short ushort_t;
typedef __attribute__((ext_vector_type(8))) short short8;
typedef __attribute__((ext_vector_type(4))) float f32x4;

__device__ __forceinline__ float bf2f(ushort_t u) {
    union { unsigned int i; float f; } x; x.i = ((unsigned int)u) << 16; return x.f;
}
__device__ __forceinline__ ushort_t f2bf(float f) {
    union { float f; unsigned int i; } x; x.f = f;
    unsigned int lsb = (x.i >> 16) & 1u;
    x.i += 0x7fffu + lsb;   // round-to-nearest-even
    return (ushort_t)(x.i >> 16);
}

__device__ __forceinline__ void load_lds16(const void* g, void* l) {
    __builtin_amdgcn_global_load_lds(
        (const __attribute__((address_space(1))) int*)g,
        (__attribute__((address_space(3))) int*)l, 16, 0, 0);
}

// ---------------------------------------------------------------------------
// x f32 -> bf16 (same layout)
// ---------------------------------------------------------------------------
__global__ __launch_bounds__(256) void cvt_k(const float* __restrict__ X,
                                             ushort_t* __restrict__ Xb, int n4)
{
    int i = blockIdx.x * blockDim.x + threadIdx.x;
    int stride = gridDim.x * blockDim.x;
    for (; i < n4; i += stride) {
        float4 v = ((const float4*)X)[i];
        ushort4 u;
        u.x = f2bf(v.x); u.y = f2bf(v.y); u.z = f2bf(v.z); u.w = f2bf(v.w);
        ((ushort4*)Xb)[i] = u;
    }
}

// ---------------------------------------------------------------------------
// W f32 [K,N] -> WT bf16 [N,K]
// ---------------------------------------------------------------------------
__global__ __launch_bounds__(256) void wt_k(const float* __restrict__ W,
                                            ushort_t* __restrict__ WT)
{
    __shared__ float tile[32][33];
    int tx = threadIdx.x & 31, ty = threadIdx.x >> 5;
    int kb = blockIdx.x << 5, nb = blockIdx.y << 5;
#pragma unroll
    for (int i = 0; i < 4; i++)
        tile[ty + i * 8][tx] = W[(size_t)(kb + ty + i * 8) * DMODEL + nb + tx];
    __syncthreads();
#pragma unroll
    for (int i = 0; i < 4; i++)
        WT[(size_t)(nb + ty + i * 8) * DMODEL + kb + tx] = f2bf(tile[tx][ty + i * 8]);
}

// ---------------------------------------------------------------------------
// MFMA GEMM, 3-slot ring + counted vmcnt + 2-phase interleave + setprio (T5).
// 256x256 tile, BK=32, 8 waves (2M x 4N), 16x16x32 bf16 MFMA.
// LDS: 3 slots x (A[4][256][8] | B[4][256][8]) = 96 KB, conflict-free reads.
// Tile t body:
//   phase A: STAGE-pair0(t+2) ; read bf[0..3], af[0..3] ; prio1 ; 16 MFMA ; prio0
//   phase B: STAGE-pair1(t+2) ; read af[4..7]           ; prio1 ; 16 MFMA ; prio0
//   s_waitcnt vmcnt(4) (t+1 landed, t+2 in flight) ; lgkmcnt(0) ;
//   sched_barrier ; s_barrier.   Never drains vmcnt to 0 mid-loop.
// MODE 0: fused QKV. N=3072 over [WTq|WTk|WTv]; feature(elu+1) for n<2048;
//         bf16 scatter to Qb/Kb/Vb in [b,h,t,d].
// MODE 2: +bias, f32 row-major [M,N].
// ---------------------------------------------------------------------------
#define TBM 256
#define TBN 256
#define TBK 32

template<int MODE>
__global__ __launch_bounds__(512, 2) void mgemm3_k(const ushort_t* __restrict__ Ap,
                                                   const ushort_t* __restrict__ Bt,
                                                   const float* __restrict__ bias,
                                                   void* __restrict__ Cp,
                                                   int M, int N, int K)
{
    __shared__ short smem[49152];              // 3 x (A 8192 | B 8192) shorts
    const int tid = threadIdx.x;
    const int l  = tid & 63;
    const int w  = tid >> 6;
    const int wm = w >> 2, wn = w & 3;         // 2 x 4 wave grid
    const int lr = l & 15;
    const int kc = l >> 4;

    const size_t m0 = (size_t)blockIdx.x * TBM;
    const size_t n0 = (size_t)blockIdx.y * TBN;

    f32x4 acc[8][4];
#pragma unroll
    for (int i = 0; i < 8; i++)
#pragma unroll
        for (int j = 0; j < 4; j++) acc[i][j] = (f32x4){0.f, 0.f, 0.f, 0.f};

    auto STAGE_PAIR = [&](int slot, int k0, int i) {
        short* Asl = smem + slot * 16384;
        short* Bsl = Asl + 8192;
        const int sa  = w * 2 + i;              // 0..15 segments of 1KB
        const int kch = sa >> 2;                // k-chunk 0..3
        const int rb  = sa & 3;                 // row-block of 64
        const int ldso = (kch * 256 + rb * 64) * 8;
        load_lds16(Ap + (m0 + rb * 64 + l) * (size_t)K + k0 + kch * 8, Asl + ldso);
        load_lds16(Bt + (n0 + rb * 64 + l) * (size_t)K + k0 + kch * 8, Bsl + ldso);
    };

    const int nt = K / TBK;                     // 32 for K=1024
    STAGE_PAIR(0, 0, 0);   STAGE_PAIR(0, 0, 1);
    STAGE_PAIR(1, TBK, 0); STAGE_PAIR(1, TBK, 1);
    asm volatile("s_waitcnt vmcnt(4)" ::: "memory");   // slot0 landed; slot1 in flight
    __builtin_amdgcn_sched_barrier(0);
    __builtin_amdgcn_s_barrier();

    for (int t = 0; t < nt; ++t) {
        const short* Asl = smem + (t % 3) * 16384;
        const short* Bsl = Asl + 8192;
        const bool pre = (t + 2 < nt);
        const int pslot = (t + 2) % 3;
        const int pk0 = (t + 2) * TBK;

        // ---- phase A: stage pair 0, read B-frags + A-half 0, MFMA m0-3 ----
        if (pre) STAGE_PAIR(pslot, pk0, 0);
        short8 bf[4], af0[4];
#pragma unroll
        for (int nn = 0; nn < 4; nn++)
            bf[nn] = *(const short8*)(Bsl + (kc * 256 + wn * 64 + nn * 16 + lr) * 8);
#pragma unroll
        for (int mt = 0; mt < 4; mt++)
            af0[mt] = *(const short8*)(Asl + (kc * 256 + wm * 128 + mt * 16 + lr) * 8);
        __builtin_amdgcn_s_setprio(1);
#pragma unroll
        for (int mt = 0; mt < 4; mt++)
#pragma unroll
            for (int nn = 0; nn < 4; nn++)
                acc[mt][nn] = __builtin_amdgcn_mfma_f32_16x16x32_bf16(
                    af0[mt], bf[nn], acc[mt][nn], 0, 0, 0);
        __builtin_amdgcn_s_setprio(0);

        // ---- phase B: stage pair 1, read A-half 1, MFMA m4-7 ----
        if (pre) STAGE_PAIR(pslot, pk0, 1);
        short8 af1[4];
#pragma unroll
        for (int mt = 0; mt < 4; mt++)
            af1[mt] = *(const short8*)(Asl + (kc * 256 + wm * 128 + (4 + mt) * 16 + lr) * 8);
        __builtin_amdgcn_s_setprio(1);
#pragma unroll
        for (int mt = 0; mt < 4; mt++)
#pragma unroll
            for (int nn = 0; nn < 4; nn++)
                acc[4 + mt][nn] = __builtin_amdgcn_mfma_f32_16x16x32_bf16(
                    af1[mt], bf[nn], acc[4 + mt][nn], 0, 0, 0);
        __builtin_amdgcn_s_setprio(0);

        if (pre) {
            asm volatile("s_waitcnt vmcnt(4)" ::: "memory");   // t+1 landed
        } else {
            asm volatile("s_waitcnt vmcnt(0)" ::: "memory");   // tail drain
        }
        asm volatile("s_waitcnt lgkmcnt(0)" ::: "memory");     // my ds_reads done
        __builtin_amdgcn_sched_barrier(0);
        __builtin_amdgcn_s_barrier();
    }

    // epilogue: row = m0 + wm*128 + mt*16 + (l>>4)*4 + j ; col = n0 + wn*64 + nn*16 + lr
#pragma unroll
    for (int mt = 0; mt < 8; mt++) {
#pragma unroll
        for (int nn = 0; nn < 4; nn++) {
#pragma unroll
            for (int j = 0; j < 4; j++) {
                int m = (int)m0 + wm * 128 + mt * 16 + (l >> 4) * 4 + j;
                int n = (int)n0 + wn * 64 + nn * 16 + lr;
                float v = acc[mt][nn][j];
                if (MODE == 2) {
                    ((float*)Cp)[(size_t)m * N + n] = v + bias[n];
                } else {
                    if (n < 2048) v = (v > 0.f) ? (v + 1.f) : __expf(v);  // Q,K feature
                    int tns = n >> 10, nnn = n & 1023;
                    int b_ = m >> 12, t_ = m & 4095, h_ = nnn >> 6, d_ = nnn & 63;
                    ushort_t* base = (ushort_t*)Cp + (size_t)tns * BATCH * SEQ * DMODEL;
                    base[((((size_t)b_ * NH + h_) * SEQ + t_) << 6) + d_] = f2bf(v);
                }
            }
        }
    }
}

// ---------------------------------------------------------------------------
// Z[b,h,t] = 1/(sum_d Q[b,h,t,d] * cumsum_{h'<=h} K[b,h',t,d] + eps)
// ---------------------------------------------------------------------------
__global__ __launch_bounds__(64) void z_k(const ushort_t* __restrict__ Q,
                                          const ushort_t* __restrict__ K,
                                          float* __restrict__ Z)
{
    int bt = blockIdx.x;
    int b_ = bt >> 12, t_ = bt & 4095;
    int d = threadIdx.x;
    float qv[NH], kv[NH];
    size_t base = (((size_t)b_ * NH) * SEQ + t_) * DH + d;
#pragma unroll
    for (int h = 0; h < NH; h++) {
        qv[h] = bf2f(Q[base + (size_t)h * SEQ * DH]);
        kv[h] = bf2f(K[base + (size_t)h * SEQ * DH]);
    }
    float ck = 0.f;
#pragma unroll
    for (int h = 0; h < NH; h++) {
        ck += kv[h];
        float p = qv[h] * ck;
#pragma unroll
        for (int off = 1; off < 64; off <<= 1) p += __shfl_xor(p, off, 64);
        if (d == 0) Z[((size_t)b_ * NH + h) * SEQ + t_] = 1.f / (p + FEPS);
    }
}

// ---------------------------------------------------------------------------
// Per-chunk S_local = K_c^T V_c  via MFMA
// ---------------------------------------------------------------------------
__global__ __launch_bounds__(256) void kv_k(const ushort_t* __restrict__ Kf,
                                            const ushort_t* __restrict__ Vf,
                                            float* __restrict__ Sloc)
{
    __shared__ short KTs[8192];
    __shared__ short VTs[8192];
    const int tid = threadIdx.x;
    const int l = tid & 63, w = tid >> 6;
    const int lr = l & 15, hi = l >> 4;
    const int blk = blockIdx.x;
    const size_t rowbase = ((size_t)(blk >> 5) * SEQ + (size_t)(blk & 31) * CHUNKSZ) * DH;
    const uint4* K16 = (const uint4*)(Kf + rowbase);
    const uint4* V16 = (const uint4*)(Vf + rowbase);
#pragma unroll
    for (int i = 0; i < 4; i++) {
        int idx = tid + i * 256;
        union { uint4 q; ushort_t us[8]; } kk, vv;
        kk.q = K16[idx]; vv.q = V16[idx];
        int j = idx >> 3, e0 = (idx & 7) << 3;
#pragma unroll
        for (int s = 0; s < 8; s++) {
            int off = ((j >> 3) * 64 + e0 + s) * 8 + (j & 7);
            KTs[off] = (short)kk.us[s];
            VTs[off] = (short)vv.us[s];
        }
    }
    __syncthreads();
    f32x4 acc[4];
#pragma unroll
    for (int nt = 0; nt < 4; nt++) acc[nt] = (f32x4){0.f, 0.f, 0.f, 0.f};
#pragma unroll
    for (int ks = 0; ks < 4; ks++) {
        short8 af = *(const short8*)(KTs + ((ks * 4 + hi) * 64 + w * 16 + lr) * 8);
        short8 bf[4];
#pragma unroll
        for (int nt = 0; nt < 4; nt++)
            bf[nt] = *(const short8*)(VTs + ((ks * 4 + hi) * 64 + nt * 16 + lr) * 8);
#pragma unroll
        for (int nt = 0; nt < 4; nt++)
            acc[nt] = __builtin_amdgcn_mfma_f32_16x16x32_bf16(af, bf[nt], acc[nt], 0, 0, 0);
    }
    float* outp = Sloc + (size_t)blk * DH * DH;
#pragma unroll
    for (int nt = 0; nt < 4; nt++)
#pragma unroll
        for (int jr = 0; jr < 4; jr++) {
            int d_ = w * 16 + hi * 4 + jr;
            int e_ = nt * 16 + lr;
            outp[d_ * DH + e_] = acc[nt][jr];
        }
}

// ---------------------------------------------------------------------------
// Exclusive prefix over chunks, element-parallel
// ---------------------------------------------------------------------------
__global__ __launch_bounds__(256) void scan_k(float* __restrict__ Sloc)
{
    int bh = blockIdx.x, seg = blockIdx.y;
    int e = seg * 256 + threadIdx.x;
    float* base = Sloc + (size_t)bh * NCHUNK * DH * DH + e;
    float acc = 0.f;
    float cur = base[0];
    for (int cc = 0; cc < NCHUNK; cc++) {
        float nxt = (cc + 1 < NCHUNK) ? base[(size_t)(cc + 1) * DH * DH] : 0.f;
        base[(size_t)cc * DH * DH] = acc;
        acc += cur;
        cur = nxt;
    }
}

// ---------------------------------------------------------------------------
// MFMA attention chunk kernel (validated round 3)
// ---------------------------------------------------------------------------
__global__ __launch_bounds__(256) void attn_k(const ushort_t* __restrict__ Qf,
                                              const ushort_t* __restrict__ Kf,
                                              const ushort_t* __restrict__ Vf,
                                              const float* __restrict__ Sloc,
                                              const float* __restrict__ Z,
                                              ushort_t* __restrict__ A)
{
    __shared__ short smem[36864];
    short* Qs  = smem;
    short* Ks  = smem + 8192;
    short* Ps  = smem + 8192;
    short* VTs = smem + 24576;
    short* STs = smem + 32768;

    const int tid = threadIdx.x;
    const int l = tid & 63, w = tid >> 6;
    const int lr = l & 15, hi = l >> 4;
    const int blk = blockIdx.x;
    const int c = blk & (NCHUNK - 1), bh = blk >> 5;
    const int b_ = bh >> 4, h_ = bh & 15;
    const size_t rowbase = ((size_t)bh * SEQ + (size_t)c * CHUNKSZ) * DH;

#pragma unroll
    for (int ii = 0; ii < 4; ii++) {
        int s = w * 4 + ii;
        int kc2 = s >> 1, rh = (s & 1) << 6;
        int ldso = (kc2 * 128 + rh) * 8;
        load_lds16(Qf + rowbase + (size_t)(rh + l) * DH + kc2 * 8, Qs + ldso);
        load_lds16(Kf + rowbase + (size_t)(rh + l) * DH + kc2 * 8, Ks + ldso);
    }
    {
        const uint4* V16 = (const uint4*)(Vf + rowbase);
#pragma unroll
        for (int i = 0; i < 4; i++) {
            int idx = tid + i * 256;
            union { uint4 q; ushort_t us[8]; } vv;
            vv.q = V16[idx];
            int j = idx >> 3, e0 = (idx & 7) << 3;
#pragma unroll
            for (int s = 0; s < 8; s++)
                VTs[((j >> 3) * 64 + e0 + s) * 8 + (j & 7)] = (short)vv.us[s];
        }
    }
    {
        const float4* S16 = (const float4*)(Sloc + (size_t)blk * DH * DH);
#pragma unroll
        for (int i = 0; i < 4; i++) {
            int idx = tid + i * 256;
            float4 f = S16[idx];
            int d = idx >> 4, e0 = (idx & 15) << 2;
            STs[((d >> 3) * 64 + e0 + 0) * 8 + (d & 7)] = (short)f2bf(f.x);
            STs[((d >> 3) * 64 + e0 + 1) * 8 + (d & 7)] = (short)f2bf(f.y);
            STs[((d >> 3) * 64 + e0 + 2) * 8 + (d & 7)] = (short)f2bf(f.z);
            STs[((d >> 3) * 64 + e0 + 3) * 8 + (d & 7)] = (short)f2bf(f.w);
        }
    }
    __syncthreads();

    f32x4 acc1[2][8];
#pragma unroll
    for (int mt = 0; mt < 2; mt++)
#pragma unroll
        for (int nt = 0; nt < 8; nt++) acc1[mt][nt] = (f32x4){0.f, 0.f, 0.f, 0.f};
#pragma unroll
    for (int ks = 0; ks < 2; ks++) {
        short8 af[2], bf[8];
#pragma unroll
        for (int mt = 0; mt < 2; mt++)
            af[mt] = *(const short8*)(Qs + ((ks * 4 + hi) * 128 + w * 32 + mt * 16 + lr) * 8);
#pragma unroll
        for (int nt = 0; nt < 8; nt++)
            bf[nt] = *(const short8*)(Ks + ((ks * 4 + hi) * 128 + nt * 16 + lr) * 8);
#pragma unroll
        for (int mt = 0; mt < 2; mt++)
#pragma unroll
            for (int nt = 0; nt < 8; nt++)
                acc1[mt][nt] = __builtin_amdgcn_mfma_f32_16x16x32_bf16(
                    af[mt], bf[nt], acc1[mt][nt], 0, 0, 0);
    }
    __syncthreads();

#pragma unroll
    for (int mt = 0; mt < 2; mt++)
#pragma unroll
        for (int nt = 0; nt < 8; nt++)
#pragma unroll
            for (int jr = 0; jr < 4; jr++) {
                int i_ = w * 32 + mt * 16 + hi * 4 + jr;
                int j_ = nt * 16 + lr;
                float v = (j_ <= i_) ? acc1[mt][nt][jr] : 0.f;
                Ps[((j_ >> 3) * 128 + i_) * 8 + (j_ & 7)] = (short)f2bf(v);
            }
    __syncthreads();

    f32x4 acc2[2][4];
#pragma unroll
    for (int mt = 0; mt < 2; mt++)
#pragma unroll
        for (int nt = 0; nt < 4; nt++) acc2[mt][nt] = (f32x4){0.f, 0.f, 0.f, 0.f};
#pragma unroll
    for (int ks = 0; ks < 4; ks++) {
        short8 af[2], bf[4];
#pragma unroll
        for (int mt = 0; mt < 2; mt++)
            af[mt] = *(const short8*)(Ps + ((ks * 4 + hi) * 128 + w * 32 + mt * 16 + lr) * 8);
#pragma unroll
        for (int nt = 0; nt < 4; nt++)
            bf[nt] = *(const short8*)(VTs + ((ks * 4 + hi) * 64 + nt * 16 + lr) * 8);
#pragma unroll
        for (int mt = 0; mt < 2; mt++)
#pragma unroll
            for (int nt = 0; nt < 4; nt++)
                acc2[mt][nt] = __builtin_amdgcn_mfma_f32_16x16x32_bf16(
                    af[mt], bf[nt], acc2[mt][nt], 0, 0, 0);
    }
#pragma unroll
    for (int ks = 0; ks < 2; ks++) {
        short8 af[2], bf[4];
#pragma unroll
        for (int mt = 0; mt < 2; mt++)
            af[mt] = *(const short8*)(Qs + ((ks * 4 + hi) * 128 + w * 32 + mt * 16 + lr) * 8);
#pragma unroll
        for (int nt = 0; nt < 4; nt++)
            bf[nt] = *(const short8*)(STs + ((ks * 4 + hi) * 64 + nt * 16 + lr) * 8);
#pragma unroll
        for (int mt = 0; mt < 2; mt++)
#pragma unroll
            for (int nt = 0; nt < 4; nt++)
                acc2[mt][nt] = __builtin_amdgcn_mfma_f32_16x16x32_bf16(
                    af[mt], bf[nt], acc2[mt][nt], 0, 0, 0);
    }

#pragma unroll
    for (int mt = 0; mt < 2; mt++) {
#pragma unroll
        for (int jr = 0; jr < 4; jr++) {
            int i_ = w * 32 + mt * 16 + hi * 4 + jr;
            int t_ = c * CHUNKSZ + i_;
            float z = Z[(size_t)bh * SEQ + t_];
            ushort_t* op = A + (((size_t)(b_ * SEQ + t_)) * NH + h_) * DH;
#pragma unroll
            for (int nt = 0; nt < 4; nt++)
                op[nt * 16 + lr] = f2bf(acc2[mt][nt][jr] * z);
        }
    }
}

// ---------------------------------------------------------------------------
extern "C" void kernel_launch(void* const* d_in, const int* in_sizes, int n_in,
                              void* d_out, int out_size, void* d_ws, size_t ws_size,
                              hipStream_t stream)
{
    const float* x  = (const float*)d_in[0];
    const float* Wq = (const float*)d_in[1];
    const float* Wk = (const float*)d_in[2];
    const float* Wv = (const float*)d_in[3];
    const float* Wo = (const float*)d_in[4];
    const float* bo = (const float*)d_in[5];
    float* out = (float*)d_out;

    const size_t NEL = (size_t)BATCH * SEQ * DMODEL;
    const size_t WEL = (size_t)DMODEL * DMODEL;
    ushort_t* Qb  = (ushort_t*)d_ws;                   // Q,K,V contiguous (fused scatter)
    ushort_t* Kb  = Qb + NEL;
    ushort_t* Vb  = Kb + NEL;
    ushort_t* XAb = Vb + NEL;                          // x bf16, later attn out
    float*    Zb  = (float*)(XAb + NEL);
    ushort_t* WTq = (ushort_t*)(Zb + (size_t)BATCH * NH * SEQ);  // WTq|WTk|WTv contiguous
    ushort_t* WTk = WTq + WEL;
    ushort_t* WTv = WTk + WEL;
    ushort_t* WTo = WTv + WEL;
    float*    Sl  = (float*)d_out;                     // scratch; final gemm overwrites

    const int M = BATCH * SEQ;
    dim3 gw(32, 32);

    cvt_k<<<dim3(2048), dim3(256), 0, stream>>>(x, XAb, (int)(NEL / 4));
    wt_k<<<gw, dim3(256), 0, stream>>>(Wq, WTq);
    wt_k<<<gw, dim3(256), 0, stream>>>(Wk, WTk);
    wt_k<<<gw, dim3(256), 0, stream>>>(Wv, WTv);
    wt_k<<<gw, dim3(256), 0, stream>>>(Wo, WTo);

    // fused QKV: N = 3072 over concatenated [WTq|WTk|WTv]
    mgemm3_k<0><<<dim3(M / TBM, 3 * DMODEL / TBN), dim3(512), 0, stream>>>(
        XAb, WTq, nullptr, Qb, M, 3 * DMODEL, DMODEL);

    z_k<<<dim3(BATCH * SEQ), dim3(64), 0, stream>>>(Qb, Kb, Zb);

    kv_k<<<dim3(BATCH * NH * NCHUNK), dim3(256), 0, stream>>>(Kb, Vb, Sl);
    scan_k<<<dim3(BATCH * NH, 16), dim3(256), 0, stream>>>(Sl);
    attn_k<<<dim3(BATCH * NH * NCHUNK), dim3(256), 0, stream>>>(Qb, Kb, Vb, Sl, Zb, XAb);

    mgemm3_k<2><<<dim3(M / TBM, DMODEL / TBN), dim3(512), 0, stream>>>(
        XAb, WTo, bo, out, M, DMODEL, DMODEL);
}

// Round 7
// 293.927 us; speedup vs baseline: 6.6552x; 1.0375x over previous
//
#include <hip/hip_runtime.h>
#include <hip/hip_bf16.h>

#define BATCH 4
#define SEQ   4096
#define DMODEL 1024
#define NH    16
#define DH    64
#define NCHUNK 32
#define CHUNKSZ 128
#define FEPS  1e-6f

typedef unsigned short ushort_t;
typedef __attribute__((ext_vector_type(8))) short short8;
typedef __attribute__((ext_vector_type(4))) float f32x4;

__device__ __forceinline__ float bf2f(ushort_t u) {
    union { unsigned int i; float f; } x; x.i = ((unsigned int)u) << 16; return x.f;
}
__device__ __forceinline__ ushort_t f2bf(float f) {
    union { float f; unsigned int i; } x; x.f = f;
    unsigned int lsb = (x.i >> 16) & 1u;
    x.i += 0x7fffu + lsb;   // round-to-nearest-even
    return (ushort_t)(x.i >> 16);
}

__device__ __forceinline__ void load_lds16(const void* g, void* l) {
    __builtin_amdgcn_global_load_lds(
        (const __attribute__((address_space(1))) int*)g,
        (__attribute__((address_space(3))) int*)l, 16, 0, 0);
}

// ---------------------------------------------------------------------------
// x f32 -> bf16 (same layout)
// ---------------------------------------------------------------------------
__global__ __launch_bounds__(256) void cvt_k(const float* __restrict__ X,
                                             ushort_t* __restrict__ Xb, int n4)
{
    int i = blockIdx.x * blockDim.x + threadIdx.x;
    int stride = gridDim.x * blockDim.x;
    for (; i < n4; i += stride) {
        float4 v = ((const float4*)X)[i];
        ushort4 u;
        u.x = f2bf(v.x); u.y = f2bf(v.y); u.z = f2bf(v.z); u.w = f2bf(v.w);
        ((ushort4*)Xb)[i] = u;
    }
}

// ---------------------------------------------------------------------------
// All four W f32 [K,N] -> WT bf16 [N,K], one launch (blockIdx.z selects)
// ---------------------------------------------------------------------------
__global__ __launch_bounds__(256) void wt4_k(const float* __restrict__ W0,
                                             const float* __restrict__ W1,
                                             const float* __restrict__ W2,
                                             const float* __restrict__ W3,
                                             ushort_t* __restrict__ WT0)
{
    const float* Ws[4] = {W0, W1, W2, W3};
    const float* W = Ws[blockIdx.z];
    ushort_t* WT = WT0 + (size_t)blockIdx.z * DMODEL * DMODEL;
    __shared__ float tile[32][33];
    int tx = threadIdx.x & 31, ty = threadIdx.x >> 5;
    int kb = blockIdx.x << 5, nb = blockIdx.y << 5;
#pragma unroll
    for (int i = 0; i < 4; i++)
        tile[ty + i * 8][tx] = W[(size_t)(kb + ty + i * 8) * DMODEL + nb + tx];
    __syncthreads();
#pragma unroll
    for (int i = 0; i < 4; i++)
        WT[(size_t)(nb + ty + i * 8) * DMODEL + kb + tx] = f2bf(tile[tx][ty + i * 8]);
}

// ---------------------------------------------------------------------------
// MFMA GEMM, 4-slot ring + deep counted vmcnt + per-phase double barriers
// (m201-style schedule on the validated [kc][row][8] conflict-free layout).
// 256x256 tile, BK=32, 8 waves (2M x 4N), 16x16x32 bf16 MFMA.
// LDS: 4 slots x (A[4][256][8] | B[4][256][8]) = 128 KB -> 1 block/CU.
// Iter t (phases A/B):
//   A: STAGE-pair0(t+3) ; ds_read bf[0..3]+af0 ; SBAR ; bar ; lgkm0 ; SBAR ;
//      prio1 ; 16 MFMA (mt0-3) ; prio0 ; bar
//   B: STAGE-pair1(t+3) ; ds_read af1 ; SBAR ; bar ; lgkm0 ; SBAR ;
//      prio1 ; 16 MFMA (mt4-7) ; prio0
//   tile boundary: vmcnt(8) (t+1 landed; t+2,t+3 in flight; tail 4->0) ; bar
// Race invariants: slot(t+3)=slot(t-1) last read before iter t-1's closing
// barrier (lgkm0 precedes MFMA precedes barrier) -> WAR safe. vmcnt(8) before
// the tile barrier -> tile t+1 writes landed before any read -> RAW safe.
// MODE 0: fused QKV. N=3072 over [WTq|WTk|WTv]; feature(elu+1) for n<2048;
//         bf16 scatter to Qb/Kb/Vb in [b,h,t,d].
// MODE 2: +bias, f32 row-major [M,N].
// ---------------------------------------------------------------------------
#define TBM 256
#define TBN 256
#define TBK 32

template<int MODE>
__global__ __launch_bounds__(512, 2) void mgemm8_k(const ushort_t* __restrict__ Ap,
                                                   const ushort_t* __restrict__ Bt,
                                                   const float* __restrict__ bias,
                                                   void* __restrict__ Cp,
                                                   int M, int N, int K)
{
    __shared__ short smem[65536];              // 4 x (A 8192 | B 8192) shorts
    const int tid = threadIdx.x;
    const int l  = tid & 63;
    const int w  = tid >> 6;
    const int wm = w >> 2, wn = w & 3;         // 2 x 4 wave grid
    const int lr = l & 15;
    const int kc = l >> 4;

    const size_t m0 = (size_t)blockIdx.x * TBM;
    const size_t n0 = (size_t)blockIdx.y * TBN;

    f32x4 acc[8][4];
#pragma unroll
    for (int i = 0; i < 8; i++)
#pragma unroll
        for (int j = 0; j < 4; j++) acc[i][j] = (f32x4){0.f, 0.f, 0.f, 0.f};

    auto STAGE_PAIR = [&](int slot, int k0, int i) {
        short* Asl = smem + slot * 16384;
        short* Bsl = Asl + 8192;
        const int sa  = w * 2 + i;              // 0..15 segments of 1KB
        const int kch = sa >> 2;                // k-chunk 0..3
        const int rb  = sa & 3;                 // row-block of 64
        const int ldso = (kch * 256 + rb * 64) * 8;
        load_lds16(Ap + (m0 + rb * 64 + l) * (size_t)K + k0 + kch * 8, Asl + ldso);
        load_lds16(Bt + (n0 + rb * 64 + l) * (size_t)K + k0 + kch * 8, Bsl + ldso);
    };

    const int nt = K / TBK;                     // 32 for K=1024
    STAGE_PAIR(0, 0, 0);       STAGE_PAIR(0, 0, 1);
    STAGE_PAIR(1, TBK, 0);     STAGE_PAIR(1, TBK, 1);
    STAGE_PAIR(2, 2 * TBK, 0); STAGE_PAIR(2, 2 * TBK, 1);
    asm volatile("s_waitcnt vmcnt(8)" ::: "memory");   // tile0 landed; 1,2 in flight
    __builtin_amdgcn_sched_barrier(0);
    __builtin_amdgcn_s_barrier();

    for (int t = 0; t < nt; ++t) {
        const short* Asl = smem + (t & 3) * 16384;
        const short* Bsl = Asl + 8192;
        const bool pre = (t + 3 < nt);
        const int pslot = (t + 3) & 3;
        const int pk0 = (t + 3) * TBK;

        // ---------------- phase A ----------------
        if (pre) STAGE_PAIR(pslot, pk0, 0);
        short8 bf[4], af0[4];
#pragma unroll
        for (int nn = 0; nn < 4; nn++)
            bf[nn] = *(const short8*)(Bsl + (kc * 256 + wn * 64 + nn * 16 + lr) * 8);
#pragma unroll
        for (int mt = 0; mt < 4; mt++)
            af0[mt] = *(const short8*)(Asl + (kc * 256 + wm * 128 + mt * 16 + lr) * 8);
        __builtin_amdgcn_sched_barrier(0);
        __builtin_amdgcn_s_barrier();
        asm volatile("s_waitcnt lgkmcnt(0)" ::: "memory");
        __builtin_amdgcn_sched_barrier(0);
        __builtin_amdgcn_s_setprio(1);
#pragma unroll
        for (int mt = 0; mt < 4; mt++)
#pragma unroll
            for (int nn = 0; nn < 4; nn++)
                acc[mt][nn] = __builtin_amdgcn_mfma_f32_16x16x32_bf16(
                    af0[mt], bf[nn], acc[mt][nn], 0, 0, 0);
        __builtin_amdgcn_s_setprio(0);
        __builtin_amdgcn_s_barrier();

        // ---------------- phase B ----------------
        if (pre) STAGE_PAIR(pslot, pk0, 1);
        short8 af1[4];
#pragma unroll
        for (int mt = 0; mt < 4; mt++)
            af1[mt] = *(const short8*)(Asl + (kc * 256 + wm * 128 + (4 + mt) * 16 + lr) * 8);
        __builtin_amdgcn_sched_barrier(0);
        __builtin_amdgcn_s_barrier();
        asm volatile("s_waitcnt lgkmcnt(0)" ::: "memory");
        __builtin_amdgcn_sched_barrier(0);
        __builtin_amdgcn_s_setprio(1);
#pragma unroll
        for (int mt = 0; mt < 4; mt++)
#pragma unroll
            for (int nn = 0; nn < 4; nn++)
                acc[4 + mt][nn] = __builtin_amdgcn_mfma_f32_16x16x32_bf16(
                    af1[mt], bf[nn], acc[4 + mt][nn], 0, 0, 0);
        __builtin_amdgcn_s_setprio(0);

        // ---------------- tile boundary ----------------
        if (t + 3 < nt) {
            asm volatile("s_waitcnt vmcnt(8)" ::: "memory");   // t+1 landed
        } else if (t + 2 < nt) {
            asm volatile("s_waitcnt vmcnt(4)" ::: "memory");
        } else if (t + 1 < nt) {
            asm volatile("s_waitcnt vmcnt(0)" ::: "memory");
        }
        __builtin_amdgcn_sched_barrier(0);
        __builtin_amdgcn_s_barrier();
    }

    // epilogue: row = m0 + wm*128 + mt*16 + (l>>4)*4 + j ; col = n0 + wn*64 + nn*16 + lr
#pragma unroll
    for (int mt = 0; mt < 8; mt++) {
#pragma unroll
        for (int nn = 0; nn < 4; nn++) {
#pragma unroll
            for (int j = 0; j < 4; j++) {
                int m = (int)m0 + wm * 128 + mt * 16 + (l >> 4) * 4 + j;
                int n = (int)n0 + wn * 64 + nn * 16 + lr;
                float v = acc[mt][nn][j];
                if (MODE == 2) {
                    ((float*)Cp)[(size_t)m * N + n] = v + bias[n];
                } else {
                    if (n < 2048) v = (v > 0.f) ? (v + 1.f) : __expf(v);  // Q,K feature
                    int tns = n >> 10, nnn = n & 1023;
                    int b_ = m >> 12, t_ = m & 4095, h_ = nnn >> 6, d_ = nnn & 63;
                    ushort_t* base = (ushort_t*)Cp + (size_t)tns * BATCH * SEQ * DMODEL;
                    base[((((size_t)b_ * NH + h_) * SEQ + t_) << 6) + d_] = f2bf(v);
                }
            }
        }
    }
}

// ---------------------------------------------------------------------------
// Z[b,h,t] = 1/(sum_d Q[b,h,t,d] * cumsum_{h'<=h} K[b,h',t,d] + eps)
// 4 waves per block, one (b,t) per wave
// ---------------------------------------------------------------------------
__global__ __launch_bounds__(256) void z_k(const ushort_t* __restrict__ Q,
                                           const ushort_t* __restrict__ K,
                                           float* __restrict__ Z)
{
    int bt = blockIdx.x * 4 + (threadIdx.x >> 6);
    int b_ = bt >> 12, t_ = bt & 4095;
    int d = threadIdx.x & 63;
    float qv[NH], kv[NH];
    size_t base = (((size_t)b_ * NH) * SEQ + t_) * DH + d;
#pragma unroll
    for (int h = 0; h < NH; h++) {
        qv[h] = bf2f(Q[base + (size_t)h * SEQ * DH]);
        kv[h] = bf2f(K[base + (size_t)h * SEQ * DH]);
    }
    float ck = 0.f;
#pragma unroll
    for (int h = 0; h < NH; h++) {
        ck += kv[h];
        float p = qv[h] * ck;
#pragma unroll
        for (int off = 1; off < 64; off <<= 1) p += __shfl_xor(p, off, 64);
        if (d == 0) Z[((size_t)b_ * NH + h) * SEQ + t_] = 1.f / (p + FEPS);
    }
}

// ---------------------------------------------------------------------------
// Per-chunk S_local = K_c^T V_c  via MFMA
// ---------------------------------------------------------------------------
__global__ __launch_bounds__(256) void kv_k(const ushort_t* __restrict__ Kf,
                                            const ushort_t* __restrict__ Vf,
                                            float* __restrict__ Sloc)
{
    __shared__ short KTs[8192];
    __shared__ short VTs[8192];
    const int tid = threadIdx.x;
    const int l = tid & 63, w = tid >> 6;
    const int lr = l & 15, hi = l >> 4;
    const int blk = blockIdx.x;
    const size_t rowbase = ((size_t)(blk >> 5) * SEQ + (size_t)(blk & 31) * CHUNKSZ) * DH;
    const uint4* K16 = (const uint4*)(Kf + rowbase);
    const uint4* V16 = (const uint4*)(Vf + rowbase);
#pragma unroll
    for (int i = 0; i < 4; i++) {
        int idx = tid + i * 256;
        union { uint4 q; ushort_t us[8]; } kk, vv;
        kk.q = K16[idx]; vv.q = V16[idx];
        int j = idx >> 3, e0 = (idx & 7) << 3;
#pragma unroll
        for (int s = 0; s < 8; s++) {
            int off = ((j >> 3) * 64 + e0 + s) * 8 + (j & 7);
            KTs[off] = (short)kk.us[s];
            VTs[off] = (short)vv.us[s];
        }
    }
    __syncthreads();
    f32x4 acc[4];
#pragma unroll
    for (int nt = 0; nt < 4; nt++) acc[nt] = (f32x4){0.f, 0.f, 0.f, 0.f};
#pragma unroll
    for (int ks = 0; ks < 4; ks++) {
        short8 af = *(const short8*)(KTs + ((ks * 4 + hi) * 64 + w * 16 + lr) * 8);
        short8 bf[4];
#pragma unroll
        for (int nt = 0; nt < 4; nt++)
            bf[nt] = *(const short8*)(VTs + ((ks * 4 + hi) * 64 + nt * 16 + lr) * 8);
#pragma unroll
        for (int nt = 0; nt < 4; nt++)
            acc[nt] = __builtin_amdgcn_mfma_f32_16x16x32_bf16(af, bf[nt], acc[nt], 0, 0, 0);
    }
    float* outp = Sloc + (size_t)blk * DH * DH;
#pragma unroll
    for (int nt = 0; nt < 4; nt++)
#pragma unroll
        for (int jr = 0; jr < 4; jr++) {
            int d_ = w * 16 + hi * 4 + jr;
            int e_ = nt * 16 + lr;
            outp[d_ * DH + e_] = acc[nt][jr];
        }
}

// ---------------------------------------------------------------------------
// Exclusive prefix over chunks, element-parallel
// ---------------------------------------------------------------------------
__global__ __launch_bounds__(256) void scan_k(float* __restrict__ Sloc)
{
    int bh = blockIdx.x, seg = blockIdx.y;
    int e = seg * 256 + threadIdx.x;
    float* base = Sloc + (size_t)bh * NCHUNK * DH * DH + e;
    float acc = 0.f;
    float cur = base[0];
    for (int cc = 0; cc < NCHUNK; cc++) {
        float nxt = (cc + 1 < NCHUNK) ? base[(size_t)(cc + 1) * DH * DH] : 0.f;
        base[(size_t)cc * DH * DH] = acc;
        acc += cur;
        cur = nxt;
    }
}

// ---------------------------------------------------------------------------
// MFMA attention chunk kernel (validated round 3)
// ---------------------------------------------------------------------------
__global__ __launch_bounds__(256) void attn_k(const ushort_t* __restrict__ Qf,
                                              const ushort_t* __restrict__ Kf,
                                              const ushort_t* __restrict__ Vf,
                                              const float* __restrict__ Sloc,
                                              const float* __restrict__ Z,
                                              ushort_t* __restrict__ A)
{
    __shared__ short smem[36864];
    short* Qs  = smem;
    short* Ks  = smem + 8192;
    short* Ps  = smem + 8192;
    short* VTs = smem + 24576;
    short* STs = smem + 32768;

    const int tid = threadIdx.x;
    const int l = tid & 63, w = tid >> 6;
    const int lr = l & 15, hi = l >> 4;
    const int blk = blockIdx.x;
    const int c = blk & (NCHUNK - 1), bh = blk >> 5;
    const int b_ = bh >> 4, h_ = bh & 15;
    const size_t rowbase = ((size_t)bh * SEQ + (size_t)c * CHUNKSZ) * DH;

#pragma unroll
    for (int ii = 0; ii < 4; ii++) {
        int s = w * 4 + ii;
        int kc2 = s >> 1, rh = (s & 1) << 6;
        int ldso = (kc2 * 128 + rh) * 8;
        load_lds16(Qf + rowbase + (size_t)(rh + l) * DH + kc2 * 8, Qs + ldso);
        load_lds16(Kf + rowbase + (size_t)(rh + l) * DH + kc2 * 8, Ks + ldso);
    }
    {
        const uint4* V16 = (const uint4*)(Vf + rowbase);
#pragma unroll
        for (int i = 0; i < 4; i++) {
            int idx = tid + i * 256;
            union { uint4 q; ushort_t us[8]; } vv;
            vv.q = V16[idx];
            int j = idx >> 3, e0 = (idx & 7) << 3;
#pragma unroll
            for (int s = 0; s < 8; s++)
                VTs[((j >> 3) * 64 + e0 + s) * 8 + (j & 7)] = (short)vv.us[s];
        }
    }
    {
        const float4* S16 = (const float4*)(Sloc + (size_t)blk * DH * DH);
#pragma unroll
        for (int i = 0; i < 4; i++) {
            int idx = tid + i * 256;
            float4 f = S16[idx];
            int d = idx >> 4, e0 = (idx & 15) << 2;
            STs[((d >> 3) * 64 + e0 + 0) * 8 + (d & 7)] = (short)f2bf(f.x);
            STs[((d >> 3) * 64 + e0 + 1) * 8 + (d & 7)] = (short)f2bf(f.y);
            STs[((d >> 3) * 64 + e0 + 2) * 8 + (d & 7)] = (short)f2bf(f.z);
            STs[((d >> 3) * 64 + e0 + 3) * 8 + (d & 7)] = (short)f2bf(f.w);
        }
    }
    __syncthreads();

    f32x4 acc1[2][8];
#pragma unroll
    for (int mt = 0; mt < 2; mt++)
#pragma unroll
        for (int nt = 0; nt < 8; nt++) acc1[mt][nt] = (f32x4){0.f, 0.f, 0.f, 0.f};
#pragma unroll
    for (int ks = 0; ks < 2; ks++) {
        short8 af[2], bf[8];
#pragma unroll
        for (int mt = 0; mt < 2; mt++)
            af[mt] = *(const short8*)(Qs + ((ks * 4 + hi) * 128 + w * 32 + mt * 16 + lr) * 8);
#pragma unroll
        for (int nt = 0; nt < 8; nt++)
            bf[nt] = *(const short8*)(Ks + ((ks * 4 + hi) * 128 + nt * 16 + lr) * 8);
#pragma unroll
        for (int mt = 0; mt < 2; mt++)
#pragma unroll
            for (int nt = 0; nt < 8; nt++)
                acc1[mt][nt] = __builtin_amdgcn_mfma_f32_16x16x32_bf16(
                    af[mt], bf[nt], acc1[mt][nt], 0, 0, 0);
    }
    __syncthreads();

#pragma unroll
    for (int mt = 0; mt < 2; mt++)
#pragma unroll
        for (int nt = 0; nt < 8; nt++)
#pragma unroll
            for (int jr = 0; jr < 4; jr++) {
                int i_ = w * 32 + mt * 16 + hi * 4 + jr;
                int j_ = nt * 16 + lr;
                float v = (j_ <= i_) ? acc1[mt][nt][jr] : 0.f;
                Ps[((j_ >> 3) * 128 + i_) * 8 + (j_ & 7)] = (short)f2bf(v);
            }
    __syncthreads();

    f32x4 acc2[2][4];
#pragma unroll
    for (int mt = 0; mt < 2; mt++)
#pragma unroll
        for (int nt = 0; nt < 4; nt++) acc2[mt][nt] = (f32x4){0.f, 0.f, 0.f, 0.f};
#pragma unroll
    for (int ks = 0; ks < 4; ks++) {
        short8 af[2], bf[4];
#pragma unroll
        for (int mt = 0; mt < 2; mt++)
            af[mt] = *(const short8*)(Ps + ((ks * 4 + hi) * 128 + w * 32 + mt * 16 + lr) * 8);
#pragma unroll
        for (int nt = 0; nt < 4; nt++)
            bf[nt] = *(const short8*)(VTs + ((ks * 4 + hi) * 64 + nt * 16 + lr) * 8);
#pragma unroll
        for (int mt = 0; mt < 2; mt++)
#pragma unroll
            for (int nt = 0; nt < 4; nt++)
                acc2[mt][nt] = __builtin_amdgcn_mfma_f32_16x16x32_bf16(
                    af[mt], bf[nt], acc2[mt][nt], 0, 0, 0);
    }
#pragma unroll
    for (int ks = 0; ks < 2; ks++) {
        short8 af[2], bf[4];
#pragma unroll
        for (int mt = 0; mt < 2; mt++)
            af[mt] = *(const short8*)(Qs + ((ks * 4 + hi) * 128 + w * 32 + mt * 16 + lr) * 8);
#pragma unroll
        for (int nt = 0; nt < 4; nt++)
            bf[nt] = *(const short8*)(STs + ((ks * 4 + hi) * 64 + nt * 16 + lr) * 8);
#pragma unroll
        for (int mt = 0; mt < 2; mt++)
#pragma unroll
            for (int nt = 0; nt < 4; nt++)
                acc2[mt][nt] = __builtin_amdgcn_mfma_f32_16x16x32_bf16(
                    af[mt], bf[nt], acc2[mt][nt], 0, 0, 0);
    }

#pragma unroll
    for (int mt = 0; mt < 2; mt++) {
#pragma unroll
        for (int jr = 0; jr < 4; jr++) {
            int i_ = w * 32 + mt * 16 + hi * 4 + jr;
            int t_ = c * CHUNKSZ + i_;
            float z = Z[(size_t)bh * SEQ + t_];
            ushort_t* op = A + (((size_t)(b_ * SEQ + t_)) * NH + h_) * DH;
#pragma unroll
            for (int nt = 0; nt < 4; nt++)
                op[nt * 16 + lr] = f2bf(acc2[mt][nt][jr] * z);
        }
    }
}

// ---------------------------------------------------------------------------
extern "C" void kernel_launch(void* const* d_in, const int* in_sizes, int n_in,
                              void* d_out, int out_size, void* d_ws, size_t ws_size,
                              hipStream_t stream)
{
    const float* x  = (const float*)d_in[0];
    const float* Wq = (const float*)d_in[1];
    const float* Wk = (const float*)d_in[2];
    const float* Wv = (const float*)d_in[3];
    const float* Wo = (const float*)d_in[4];
    const float* bo = (const float*)d_in[5];
    float* out = (float*)d_out;

    const size_t NEL = (size_t)BATCH * SEQ * DMODEL;
    const size_t WEL = (size_t)DMODEL * DMODEL;
    ushort_t* Qb  = (ushort_t*)d_ws;                   // Q,K,V contiguous (fused scatter)
    ushort_t* Kb  = Qb + NEL;
    ushort_t* Vb  = Kb + NEL;
    ushort_t* XAb = Vb + NEL;                          // x bf16, later attn out
    float*    Zb  = (float*)(XAb + NEL);
    ushort_t* WTq = (ushort_t*)(Zb + (size_t)BATCH * NH * SEQ);  // WTq|WTk|WTv|WTo contiguous
    ushort_t* WTo = WTq + 3 * WEL;
    float*    Sl  = (float*)d_out;                     // scratch; final gemm overwrites

    const int M = BATCH * SEQ;

    cvt_k<<<dim3(2048), dim3(256), 0, stream>>>(x, XAb, (int)(NEL / 4));
    wt4_k<<<dim3(32, 32, 4), dim3(256), 0, stream>>>(Wq, Wk, Wv, Wo, WTq);

    // fused QKV: N = 3072 over concatenated [WTq|WTk|WTv]
    mgemm8_k<0><<<dim3(M / TBM, 3 * DMODEL / TBN), dim3(512), 0, stream>>>(
        XAb, WTq, nullptr, Qb, M, 3 * DMODEL, DMODEL);

    z_k<<<dim3(BATCH * SEQ / 4), dim3(256), 0, stream>>>(Qb, Kb, Zb);

    kv_k<<<dim3(BATCH * NH * NCHUNK), dim3(256), 0, stream>>>(Kb, Vb, Sl);
    scan_k<<<dim3(BATCH * NH, 16), dim3(256), 0, stream>>>(Sl);
    attn_k<<<dim3(BATCH * NH * NCHUNK), dim3(256), 0, stream>>>(Qb, Kb, Vb, Sl, Zb, XAb);

    mgemm8_k<2><<<dim3(M / TBM, DMODEL / TBN), dim3(512), 0, stream>>>(
        XAb, WTo, bo, out, M, DMODEL, DMODEL);
}